// Round 1
// baseline (1255.915 us; speedup 1.0000x reference)
//
#include <hip/hip_runtime.h>
#include <hip/hip_bf16.h>

#define H 4
#define C 64
#define HC 256
#define FIN 128
#define FE 32
#define NCLS 16
#define BN_EPS 1e-5f

typedef __hip_bfloat16 bf16;

__device__ __forceinline__ float b2f(bf16 v) { return __bfloat162float(v); }

// order-preserving encode for float atomicMax on unsigned
__device__ __forceinline__ unsigned fenc(float f) {
    unsigned u = __float_as_uint(f);
    return (u & 0x80000000u) ? ~u : (u | 0x80000000u);
}
__device__ __forceinline__ float fdec(unsigned e) {
    unsigned u = (e & 0x80000000u) ? (e & 0x7fffffffu) : ~e;
    return __uint_as_float(u);
}

// ---------------- q,k,v projection: [N,128] x [128,256] x3 ----------------
__global__ __launch_bounds__(256) void qkv_kernel(
    const float* __restrict__ x,
    const float* __restrict__ Wq, const float* __restrict__ bq,
    const float* __restrict__ Wk, const float* __restrict__ bk,
    const float* __restrict__ Wv, const float* __restrict__ bv,
    bf16* __restrict__ q, bf16* __restrict__ k, bf16* __restrict__ v, int N)
{
    __shared__ float xs[8][FIN];
    const int t = threadIdx.x;
    const int n0 = blockIdx.x * 8;
    for (int i = t; i < 8 * FIN; i += 256) {
        int nd = i >> 7, f = i & 127;
        int n = n0 + nd;
        xs[nd][f] = (n < N) ? x[(size_t)n * FIN + f] : 0.f;
    }
    __syncthreads();
    float aq[8], ak[8], av[8];
#pragma unroll
    for (int i = 0; i < 8; ++i) { aq[i] = 0.f; ak[i] = 0.f; av[i] = 0.f; }
    for (int f = 0; f < FIN; ++f) {
        float wq = Wq[f * HC + t];
        float wk = Wk[f * HC + t];
        float wv = Wv[f * HC + t];
#pragma unroll
        for (int i = 0; i < 8; ++i) {
            float xv = xs[i][f];
            aq[i] += xv * wq;
            ak[i] += xv * wk;
            av[i] += xv * wv;
        }
    }
    float bqv = bq[t], bkv = bk[t], bvv = bv[t];
    for (int i = 0; i < 8; ++i) {
        int n = n0 + i;
        if (n < N) {
            q[(size_t)n * HC + t] = __float2bfloat16(aq[i] + bqv);
            k[(size_t)n * HC + t] = __float2bfloat16(ak[i] + bkv);
            v[(size_t)n * HC + t] = __float2bfloat16(av[i] + bvv);
        }
    }
}

// ---------------- pass 1: per-edge scores + segment max ----------------
__global__ __launch_bounds__(256) void score_kernel(
    const int* __restrict__ src, const int* __restrict__ dst,
    const float* __restrict__ ea, const float* __restrict__ We,
    const bf16* __restrict__ q, const bf16* __restrict__ k,
    float* __restrict__ score, unsigned* __restrict__ menc, int E)
{
    const int wave = (blockIdx.x * blockDim.x + threadIdx.x) >> 6;
    const int lane = threadIdx.x & 63;
    if (wave >= E) return;
    const int e = wave;
    const int s = src[e], d = dst[e];

    float eav[FE];
#pragma unroll
    for (int f = 0; f < FE; ++f) eav[f] = ea[(size_t)e * FE + f];

#pragma unroll
    for (int h = 0; h < H; ++h) {
        const int col = h * C + lane;
        float ev = 0.f;
#pragma unroll
        for (int f = 0; f < FE; ++f) ev += eav[f] * We[f * HC + col];
        float kv = b2f(k[(size_t)s * HC + col]);
        float qv = b2f(q[(size_t)d * HC + col]);
        float val = qv * (kv + ev);
#pragma unroll
        for (int off = 32; off >= 1; off >>= 1) val += __shfl_xor(val, off, 64);
        if (lane == 0) {
            float sc = val * 0.125f;  // 1/sqrt(64)
            score[(size_t)e * H + h] = sc;
            atomicMax(&menc[(size_t)d * H + h], fenc(sc));
        }
    }
}

// ---------------- pass 2: exp + segment sum ----------------
__global__ __launch_bounds__(256) void expsum_kernel(
    const int* __restrict__ dst, float* __restrict__ score,
    const unsigned* __restrict__ menc, float* __restrict__ denom, int E)
{
    const int i = blockIdx.x * 256 + threadIdx.x;
    if (i >= E * H) return;
    const int e = i >> 2, h = i & 3;
    const int d = dst[e];
    float m = fdec(menc[(size_t)d * H + h]);
    float ex = expf(score[i] - m);
    score[i] = ex;
    atomicAdd(&denom[(size_t)d * H + h], ex);
}

// ---------------- pass 3: weighted messages, head-mean folded in ----------------
__global__ __launch_bounds__(256) void msg_kernel(
    const int* __restrict__ src, const int* __restrict__ dst,
    const float* __restrict__ ea, const float* __restrict__ We,
    const bf16* __restrict__ v, const float* __restrict__ score,
    const float* __restrict__ denom, float* __restrict__ accum, int E)
{
    const int wave = (blockIdx.x * blockDim.x + threadIdx.x) >> 6;
    const int lane = threadIdx.x & 63;
    if (wave >= E) return;
    const int e = wave;
    const int s = src[e], d = dst[e];

    float eav[FE];
#pragma unroll
    for (int f = 0; f < FE; ++f) eav[f] = ea[(size_t)e * FE + f];

    float acc = 0.f;
#pragma unroll
    for (int h = 0; h < H; ++h) {
        const int col = h * C + lane;
        float ev = 0.f;
#pragma unroll
        for (int f = 0; f < FE; ++f) ev += eav[f] * We[f * HC + col];
        float vv = b2f(v[(size_t)s * HC + col]);
        float alpha = score[(size_t)e * H + h] / denom[(size_t)d * H + h];
        acc += (vv + ev) * alpha;
    }
    atomicAdd(&accum[(size_t)d * C + lane], acc * 0.25f);
}

// ---------------- final: skip GEMM + ReLU + BN + classifier ----------------
__global__ __launch_bounds__(64) void final_kernel(
    const float* __restrict__ x, const float* __restrict__ accum,
    const float* __restrict__ Wskip, const float* __restrict__ bskip,
    const float* __restrict__ gamma, const float* __restrict__ beta,
    const float* __restrict__ rmean, const float* __restrict__ rvar,
    const float* __restrict__ Wc, const float* __restrict__ bc,
    float* __restrict__ out, int N)
{
    const int n = blockIdx.x;
    const int t = threadIdx.x;
    __shared__ float xs[FIN];
    __shared__ float hbuf[C];
    xs[t] = x[(size_t)n * FIN + t];
    xs[t + 64] = x[(size_t)n * FIN + 64 + t];
    __syncthreads();

    float acc = accum[(size_t)n * C + t] + bskip[t];
    for (int f = 0; f < FIN; ++f) acc += xs[f] * Wskip[f * C + t];
    acc = fmaxf(acc, 0.f);
    acc = (acc - rmean[t]) / sqrtf(rvar[t] + BN_EPS) * gamma[t] + beta[t];
    hbuf[t] = acc;
    __syncthreads();

    if (t < NCLS) {
        float o = bc[t];
        for (int c2 = 0; c2 < C; ++c2) o += hbuf[c2] * Wc[c2 * NCLS + t];
        out[(size_t)n * NCLS + t] = o;
    }
}

extern "C" void kernel_launch(void* const* d_in, const int* in_sizes, int n_in,
                              void* d_out, int out_size, void* d_ws, size_t ws_size,
                              hipStream_t stream)
{
    const float* x     = (const float*)d_in[0];
    const int*   ei    = (const int*)d_in[1];
    const float* ea    = (const float*)d_in[2];
    const float* Wq    = (const float*)d_in[3];
    const float* bq    = (const float*)d_in[4];
    const float* Wk    = (const float*)d_in[5];
    const float* bk    = (const float*)d_in[6];
    const float* Wv    = (const float*)d_in[7];
    const float* bv    = (const float*)d_in[8];
    const float* We    = (const float*)d_in[9];
    const float* Wskip = (const float*)d_in[10];
    const float* bskip = (const float*)d_in[11];
    const float* gamma = (const float*)d_in[12];
    const float* beta  = (const float*)d_in[13];
    const float* rmean = (const float*)d_in[14];
    const float* rvar  = (const float*)d_in[15];
    const float* Wc    = (const float*)d_in[16];
    const float* bc    = (const float*)d_in[17];
    float* out = (float*)d_out;

    const int N = in_sizes[0] / FIN;
    const int E = in_sizes[2] / FE;
    const int* srcp = ei;
    const int* dstp = ei + E;

    // workspace layout (all 256B-aligned)
    char* w = (char*)d_ws;
    size_t off = 0;
    auto alloc = [&](size_t bytes) { void* p = w + off; off += (bytes + 255) & ~255ull; return p; };
    bf16*     qb    = (bf16*)alloc((size_t)N * HC * sizeof(bf16));
    bf16*     kb    = (bf16*)alloc((size_t)N * HC * sizeof(bf16));
    bf16*     vb    = (bf16*)alloc((size_t)N * HC * sizeof(bf16));
    float*    score = (float*)alloc((size_t)E * H * sizeof(float));
    unsigned* menc  = (unsigned*)alloc((size_t)N * H * sizeof(unsigned));
    float*    denom = (float*)alloc((size_t)N * H * sizeof(float));
    float*    accum = (float*)alloc((size_t)N * C * sizeof(float));

    hipMemsetAsync(menc,  0, (size_t)N * H * sizeof(unsigned), stream);
    hipMemsetAsync(denom, 0, (size_t)N * H * sizeof(float), stream);
    hipMemsetAsync(accum, 0, (size_t)N * C * sizeof(float), stream);

    qkv_kernel<<<(N + 7) / 8, 256, 0, stream>>>(x, Wq, bq, Wk, bk, Wv, bv, qb, kb, vb, N);
    score_kernel<<<(E + 3) / 4, 256, 0, stream>>>(srcp, dstp, ea, We, qb, kb, score, menc, E);
    expsum_kernel<<<(E * H + 255) / 256, 256, 0, stream>>>(dstp, score, menc, denom, E);
    msg_kernel<<<(E + 3) / 4, 256, 0, stream>>>(srcp, dstp, ea, We, vb, score, denom, accum, E);
    final_kernel<<<N, 64, 0, stream>>>(x, accum, Wskip, bskip, gamma, beta, rmean, rvar, Wc, bc, out, N);
}

// Round 2
// 909.916 us; speedup vs baseline: 1.3803x; 1.3803x over previous
//
#include <hip/hip_runtime.h>
#include <hip/hip_bf16.h>

#define H 4
#define C 64
#define HC 256
#define FIN 128
#define FE 32
#define NCLS 16
#define BN_EPS 1e-5f

typedef __hip_bfloat16 bf16;

__device__ __forceinline__ float b2f(bf16 v) { return __bfloat162float(v); }

// ------- q,k,v projection + fused qWe = per-head q @ We^T -------
// qWe[n, h*32+f] = sum_c q[n,h,c] * We[f, h*64+c]
__global__ __launch_bounds__(256) void qkv_kernel(
    const float* __restrict__ x,
    const float* __restrict__ Wq, const float* __restrict__ bq,
    const float* __restrict__ Wk, const float* __restrict__ bk,
    const float* __restrict__ Wv, const float* __restrict__ bv,
    const float* __restrict__ We,
    bf16* __restrict__ q, bf16* __restrict__ k, bf16* __restrict__ v,
    float* __restrict__ qWe, int N)
{
    __shared__ float xs[8][FIN];
    __shared__ float qs[8][HC];
    const int t = threadIdx.x;
    const int n0 = blockIdx.x * 8;
    for (int i = t; i < 8 * FIN; i += 256) {
        int nd = i >> 7, f = i & 127;
        int n = n0 + nd;
        xs[nd][f] = (n < N) ? x[(size_t)n * FIN + f] : 0.f;
    }
    __syncthreads();
    float aq[8], ak[8], av[8];
#pragma unroll
    for (int i = 0; i < 8; ++i) { aq[i] = 0.f; ak[i] = 0.f; av[i] = 0.f; }
    for (int f = 0; f < FIN; ++f) {
        float wq = Wq[f * HC + t];
        float wk = Wk[f * HC + t];
        float wv = Wv[f * HC + t];
#pragma unroll
        for (int i = 0; i < 8; ++i) {
            float xv = xs[i][f];
            aq[i] += xv * wq;
            ak[i] += xv * wk;
            av[i] += xv * wv;
        }
    }
    float bqv = bq[t], bkv = bk[t], bvv = bv[t];
#pragma unroll
    for (int i = 0; i < 8; ++i) {
        float qv = aq[i] + bqv;
        qs[i][t] = qv;
        int n = n0 + i;
        if (n < N) {
            q[(size_t)n * HC + t] = __float2bfloat16(qv);
            k[(size_t)n * HC + t] = __float2bfloat16(ak[i] + bkv);
            v[(size_t)n * HC + t] = __float2bfloat16(av[i] + bvv);
        }
    }
    __syncthreads();
    // qWe: 8 nodes x 128 (h,f) outputs = 1024, 4 per thread
#pragma unroll
    for (int r = 0; r < 4; ++r) {
        int o = r * 256 + t;
        int nd = o >> 7, rem = o & 127;
        int h = rem >> 5, f = rem & 31;
        float acc = 0.f;
        const float* wrow = We + (size_t)f * HC + h * C;
        const float* qrow = &qs[nd][h * C];
#pragma unroll
        for (int c = 0; c < C; ++c) acc += qrow[c] * wrow[c];
        int n = n0 + nd;
        if (n < N) qWe[(size_t)n * 128 + rem] = acc;
    }
}

// ------- edge pass 1: score + exp + denom (no segment-max; scores are O(1)) -------
__global__ __launch_bounds__(256) void score_kernel(
    const int* __restrict__ src, const int* __restrict__ dst,
    const float* __restrict__ ea, const float* __restrict__ qWe,
    const bf16* __restrict__ q, const bf16* __restrict__ k,
    float* __restrict__ ex, float* __restrict__ denom, int E)
{
    const int e = (blockIdx.x * blockDim.x + threadIdx.x) >> 6;
    const int lane = threadIdx.x & 63;
    if (e >= E) return;
    const int s = src[e], d = dst[e];

    const float eav = ea[(size_t)e * FE + (lane & 31)];
    float sc[H];
#pragma unroll
    for (int h = 0; h < H; ++h) {
        const int col = h * C + lane;
        float p = b2f(q[(size_t)d * HC + col]) * b2f(k[(size_t)s * HC + col]);
        if (lane < FE) p += eav * qWe[(size_t)d * 128 + h * FE + lane];
#pragma unroll
        for (int off = 32; off >= 1; off >>= 1) p += __shfl_xor(p, off, 64);
        sc[h] = expf(p * 0.125f);   // 1/sqrt(64)
    }
    if (lane == 0) {
        float4 sv = make_float4(sc[0], sc[1], sc[2], sc[3]);
        *(float4*)(ex + (size_t)e * H) = sv;
    }
    if (lane < H) {
        float val = (lane == 0) ? sc[0] : (lane == 1) ? sc[1] : (lane == 2) ? sc[2] : sc[3];
        atomicAdd(&denom[(size_t)d * H + lane], val);
    }
}

// ------- edge pass 2: alpha, accumulate V-part and ea-part (head-mean folded) -------
__global__ __launch_bounds__(256) void msg_kernel(
    const int* __restrict__ src, const int* __restrict__ dst,
    const float* __restrict__ ea, const bf16* __restrict__ v,
    const float* __restrict__ ex, const float* __restrict__ denom,
    float* __restrict__ accV, float* __restrict__ aggEA, int E)
{
    const int e = (blockIdx.x * blockDim.x + threadIdx.x) >> 6;
    const int lane = threadIdx.x & 63;
    if (e >= E) return;
    const int s = src[e], d = dst[e];

    const float4 exv = *(const float4*)(ex + (size_t)e * H);
    const float4 dnv = *(const float4*)(denom + (size_t)d * H);
    const float a0 = 0.25f * exv.x / dnv.x;
    const float a1 = 0.25f * exv.y / dnv.y;
    const float a2 = 0.25f * exv.z / dnv.z;
    const float a3 = 0.25f * exv.w / dnv.w;

    const float eav = ea[(size_t)e * FE + (lane & 31)];

    float acc = a0 * b2f(v[(size_t)s * HC + 0 * C + lane])
              + a1 * b2f(v[(size_t)s * HC + 1 * C + lane])
              + a2 * b2f(v[(size_t)s * HC + 2 * C + lane])
              + a3 * b2f(v[(size_t)s * HC + 3 * C + lane]);
    atomicAdd(&accV[(size_t)d * C + lane], acc);

    // aggEA[d, h*32+f]: idx = r*64 + lane, h = idx>>5, f = idx&31
    atomicAdd(&aggEA[(size_t)d * 128 + lane],      ((lane >> 5) ? a1 : a0) * eav);
    atomicAdd(&aggEA[(size_t)d * 128 + 64 + lane], ((lane >> 5) ? a3 : a2) * eav);
}

// ------- final: + aggEA@We + skip GEMM + ReLU + BN + classifier -------
__global__ __launch_bounds__(64) void final_kernel(
    const float* __restrict__ x, const float* __restrict__ accV,
    const float* __restrict__ aggEA, const float* __restrict__ We,
    const float* __restrict__ Wskip, const float* __restrict__ bskip,
    const float* __restrict__ gamma, const float* __restrict__ beta,
    const float* __restrict__ rmean, const float* __restrict__ rvar,
    const float* __restrict__ Wc, const float* __restrict__ bc,
    float* __restrict__ out, int N)
{
    const int n = blockIdx.x;
    const int t = threadIdx.x;
    __shared__ float xs[FIN];
    __shared__ float ags[128];
    __shared__ float hbuf[C];
    xs[t] = x[(size_t)n * FIN + t];
    xs[t + 64] = x[(size_t)n * FIN + 64 + t];
    ags[t] = aggEA[(size_t)n * 128 + t];
    ags[t + 64] = aggEA[(size_t)n * 128 + 64 + t];
    __syncthreads();

    float acc = accV[(size_t)n * C + t] + bskip[t];
#pragma unroll 8
    for (int f = 0; f < FIN; ++f) acc += xs[f] * Wskip[f * C + t];
    // aggEA @ We  (sum over h,f): We[f, h*64+t]
#pragma unroll 8
    for (int idx = 0; idx < 128; ++idx) {
        int h = idx >> 5, f = idx & 31;
        acc += ags[idx] * We[f * HC + h * C + t];
    }
    acc = fmaxf(acc, 0.f);
    acc = (acc - rmean[t]) / sqrtf(rvar[t] + BN_EPS) * gamma[t] + beta[t];
    hbuf[t] = acc;
    __syncthreads();

    if (t < NCLS) {
        float o = bc[t];
#pragma unroll 8
        for (int c2 = 0; c2 < C; ++c2) o += hbuf[c2] * Wc[c2 * NCLS + t];
        out[(size_t)n * NCLS + t] = o;
    }
}

extern "C" void kernel_launch(void* const* d_in, const int* in_sizes, int n_in,
                              void* d_out, int out_size, void* d_ws, size_t ws_size,
                              hipStream_t stream)
{
    const float* x     = (const float*)d_in[0];
    const int*   ei    = (const int*)d_in[1];
    const float* ea    = (const float*)d_in[2];
    const float* Wq    = (const float*)d_in[3];
    const float* bq    = (const float*)d_in[4];
    const float* Wk    = (const float*)d_in[5];
    const float* bk    = (const float*)d_in[6];
    const float* Wv    = (const float*)d_in[7];
    const float* bv    = (const float*)d_in[8];
    const float* We    = (const float*)d_in[9];
    const float* Wskip = (const float*)d_in[10];
    const float* bskip = (const float*)d_in[11];
    const float* gamma = (const float*)d_in[12];
    const float* beta  = (const float*)d_in[13];
    const float* rmean = (const float*)d_in[14];
    const float* rvar  = (const float*)d_in[15];
    const float* Wc    = (const float*)d_in[16];
    const float* bc    = (const float*)d_in[17];
    float* out = (float*)d_out;

    const int N = in_sizes[0] / FIN;
    const int E = in_sizes[2] / FE;
    const int* srcp = ei;
    const int* dstp = ei + E;

    char* w = (char*)d_ws;
    size_t off = 0;
    auto alloc = [&](size_t bytes) { void* p = w + off; off += (bytes + 255) & ~255ull; return p; };
    bf16*  qb    = (bf16*)alloc((size_t)N * HC * sizeof(bf16));
    bf16*  kb    = (bf16*)alloc((size_t)N * HC * sizeof(bf16));
    bf16*  vb    = (bf16*)alloc((size_t)N * HC * sizeof(bf16));
    float* qWe   = (float*)alloc((size_t)N * 128 * sizeof(float));
    float* ex    = (float*)alloc((size_t)E * H * sizeof(float));
    float* denom = (float*)alloc((size_t)N * H * sizeof(float));
    float* accV  = (float*)alloc((size_t)N * C * sizeof(float));
    float* aggEA = (float*)alloc((size_t)N * 128 * sizeof(float));

    hipMemsetAsync(denom, 0, (size_t)N * H * sizeof(float), stream);
    hipMemsetAsync(accV,  0, (size_t)N * C * sizeof(float), stream);
    hipMemsetAsync(aggEA, 0, (size_t)N * 128 * sizeof(float), stream);

    qkv_kernel<<<(N + 7) / 8, 256, 0, stream>>>(x, Wq, bq, Wk, bk, Wv, bv, We, qb, kb, vb, qWe, N);
    score_kernel<<<(E + 3) / 4, 256, 0, stream>>>(srcp, dstp, ea, qWe, qb, kb, ex, denom, E);
    msg_kernel<<<(E + 3) / 4, 256, 0, stream>>>(srcp, dstp, ea, vb, ex, denom, accV, aggEA, E);
    final_kernel<<<N, 64, 0, stream>>>(x, accV, aggEA, We, Wskip, bskip, gamma, beta, rmean, rvar, Wc, bc, out, N);
}

// Round 3
// 674.234 us; speedup vs baseline: 1.8627x; 1.3496x over previous
//
#include <hip/hip_runtime.h>
#include <hip/hip_bf16.h>

#define H 4
#define C 64
#define HC 256
#define FIN 128
#define FE 32
#define NCLS 16
#define BN_EPS 1e-5f
#define WCOLS 896   // 256 q | 256 k | 256 v | 128 qWe

typedef __hip_bfloat16 bf16;
typedef __attribute__((ext_vector_type(8))) short short8v;
typedef __attribute__((ext_vector_type(4))) float floatx4;

__device__ __forceinline__ float b2f(bf16 v) { return __bfloat162float(v); }
__device__ __forceinline__ short f2bs(float f) {
    bf16 h = __float2bfloat16(f);
    return *reinterpret_cast<short*>(&h);
}

// ------- pack weights: Wt[col][k] bf16 (transposed, B-fragment friendly) + bias[896] -------
// col<256: Wq ; <512: Wk ; <768: Wv ; >=768: Wqe[k, j=h*32+f] = sum_c Wq[k,h*64+c]*We[f,h*64+c]
__global__ __launch_bounds__(128) void pack_w_kernel(
    const float* __restrict__ Wq, const float* __restrict__ Wk, const float* __restrict__ Wv,
    const float* __restrict__ We,
    const float* __restrict__ bq, const float* __restrict__ bk, const float* __restrict__ bv,
    short* __restrict__ Wt, float* __restrict__ bias)
{
    const int col = blockIdx.x;      // 0..895
    const int t = threadIdx.x;       // 0..127 = k index
    float val;
    if (col < 256)      val = Wq[t * HC + col];
    else if (col < 512) val = Wk[t * HC + col - 256];
    else if (col < 768) val = Wv[t * HC + col - 512];
    else {
        int j = col - 768, h = j >> 5, f = j & 31;
        float acc = 0.f;
#pragma unroll 8
        for (int c = 0; c < C; ++c) acc += Wq[t * HC + h * C + c] * We[f * HC + h * C + c];
        val = acc;
    }
    Wt[(size_t)col * FIN + t] = f2bs(val);
    if (t == 0) {
        float b;
        if (col < 256)      b = bq[col];
        else if (col < 512) b = bk[col - 256];
        else if (col < 768) b = bv[col - 512];
        else {
            int j = col - 768, h = j >> 5, f = j & 31;
            float acc = 0.f;
            for (int c = 0; c < C; ++c) acc += bq[h * C + c] * We[f * HC + h * C + c];
            b = acc;
        }
        bias[col] = b;
    }
}

// ------- MFMA qkv+qWe: [N,128](fp32->bf16) x Wt[896,128]^T -> q,k,v bf16 + qWe fp32 -------
// 16 rows per block; 4 waves split the 56 col-tiles. No LDS, no barriers.
__global__ __launch_bounds__(256) void qkv_mfma_kernel(
    const float* __restrict__ x, const short* __restrict__ Wt,
    const float* __restrict__ bias,
    bf16* __restrict__ q, bf16* __restrict__ k, bf16* __restrict__ v,
    float* __restrict__ qWe, int N)
{
    const int wid = threadIdx.x >> 6;
    const int lane = threadIdx.x & 63;
    const int n0 = blockIdx.x * 16;
    const int arow = lane & 15, agrp = lane >> 4;

    // A fragments: x rows n0+arow, k = ks*32 + agrp*8 + j  (fp32 load, cvt bf16)
    int nA = n0 + arow; if (nA >= N) nA = N - 1;
    const float* xrow = x + (size_t)nA * FIN + agrp * 8;
    short8v afrag[4];
#pragma unroll
    for (int ks = 0; ks < 4; ++ks) {
        floatx4 x0 = *(const floatx4*)(xrow + ks * 32);
        floatx4 x1 = *(const floatx4*)(xrow + ks * 32 + 4);
        short8v a;
        a[0] = f2bs(x0[0]); a[1] = f2bs(x0[1]); a[2] = f2bs(x0[2]); a[3] = f2bs(x0[3]);
        a[4] = f2bs(x1[0]); a[5] = f2bs(x1[1]); a[6] = f2bs(x1[2]); a[7] = f2bs(x1[3]);
        afrag[ks] = a;
    }

    for (int ct = wid; ct < WCOLS / 16; ct += 4) {
        const int col0 = ct * 16;
        const int col = col0 + arow;
        floatx4 acc = {0.f, 0.f, 0.f, 0.f};
        const short* wp = Wt + (size_t)col * FIN + agrp * 8;
#pragma unroll
        for (int ks = 0; ks < 4; ++ks) {
            short8v b = *(const short8v*)(wp + ks * 32);
            acc = __builtin_amdgcn_mfma_f32_16x16x32_bf16(afrag[ks], b, acc, 0, 0, 0);
        }
        const float bb = bias[col];
        const int rbase = n0 + agrp * 4;
#pragma unroll
        for (int r = 0; r < 4; ++r) {
            const int n = rbase + r;
            if (n >= N) continue;
            const float val = acc[r] + bb;
            if (col0 < 256)      q[(size_t)n * HC + col]        = __float2bfloat16(val);
            else if (col0 < 512) k[(size_t)n * HC + col - 256]  = __float2bfloat16(val);
            else if (col0 < 768) v[(size_t)n * HC + col - 512]  = __float2bfloat16(val);
            else                 qWe[(size_t)n * 128 + col - 768] = val;
        }
    }
}

// ------- edge pass 1: score + exp + denom (no segment-max; scores are O(1)) -------
__global__ __launch_bounds__(256) void score_kernel(
    const int* __restrict__ src, const int* __restrict__ dst,
    const float* __restrict__ ea, const float* __restrict__ qWe,
    const bf16* __restrict__ q, const bf16* __restrict__ k,
    float* __restrict__ ex, float* __restrict__ denom, int E)
{
    const int e = (blockIdx.x * blockDim.x + threadIdx.x) >> 6;
    const int lane = threadIdx.x & 63;
    if (e >= E) return;
    const int s = src[e], d = dst[e];

    const float eav = ea[(size_t)e * FE + (lane & 31)];
    float sc[H];
#pragma unroll
    for (int h = 0; h < H; ++h) {
        const int col = h * C + lane;
        float p = b2f(q[(size_t)d * HC + col]) * b2f(k[(size_t)s * HC + col]);
        if (lane < FE) p += eav * qWe[(size_t)d * 128 + h * FE + lane];
#pragma unroll
        for (int off = 32; off >= 1; off >>= 1) p += __shfl_xor(p, off, 64);
        sc[h] = expf(p * 0.125f);   // 1/sqrt(64)
    }
    if (lane == 0) {
        float4 sv = make_float4(sc[0], sc[1], sc[2], sc[3]);
        *(float4*)(ex + (size_t)e * H) = sv;
    }
    if (lane < H) {
        float val = (lane == 0) ? sc[0] : (lane == 1) ? sc[1] : (lane == 2) ? sc[2] : sc[3];
        atomicAdd(&denom[(size_t)d * H + lane], val);
    }
}

// ------- edge pass 2: alpha, accumulate V-part and ea-part (head-mean folded) -------
__global__ __launch_bounds__(256) void msg_kernel(
    const int* __restrict__ src, const int* __restrict__ dst,
    const float* __restrict__ ea, const bf16* __restrict__ v,
    const float* __restrict__ ex, const float* __restrict__ denom,
    float* __restrict__ accV, float* __restrict__ aggEA, int E)
{
    const int e = (blockIdx.x * blockDim.x + threadIdx.x) >> 6;
    const int lane = threadIdx.x & 63;
    if (e >= E) return;
    const int s = src[e], d = dst[e];

    const float4 exv = *(const float4*)(ex + (size_t)e * H);
    const float4 dnv = *(const float4*)(denom + (size_t)d * H);
    const float a0 = 0.25f * exv.x / dnv.x;
    const float a1 = 0.25f * exv.y / dnv.y;
    const float a2 = 0.25f * exv.z / dnv.z;
    const float a3 = 0.25f * exv.w / dnv.w;

    const float eav = ea[(size_t)e * FE + (lane & 31)];

    float acc = a0 * b2f(v[(size_t)s * HC + 0 * C + lane])
              + a1 * b2f(v[(size_t)s * HC + 1 * C + lane])
              + a2 * b2f(v[(size_t)s * HC + 2 * C + lane])
              + a3 * b2f(v[(size_t)s * HC + 3 * C + lane]);
    atomicAdd(&accV[(size_t)d * C + lane], acc);

    atomicAdd(&aggEA[(size_t)d * 128 + lane],      ((lane >> 5) ? a1 : a0) * eav);
    atomicAdd(&aggEA[(size_t)d * 128 + 64 + lane], ((lane >> 5) ? a3 : a2) * eav);
}

// ------- final: + aggEA@We + skip GEMM + ReLU + BN + classifier -------
__global__ __launch_bounds__(64) void final_kernel(
    const float* __restrict__ x, const float* __restrict__ accV,
    const float* __restrict__ aggEA, const float* __restrict__ We,
    const float* __restrict__ Wskip, const float* __restrict__ bskip,
    const float* __restrict__ gamma, const float* __restrict__ beta,
    const float* __restrict__ rmean, const float* __restrict__ rvar,
    const float* __restrict__ Wc, const float* __restrict__ bc,
    float* __restrict__ out, int N)
{
    const int n = blockIdx.x;
    const int t = threadIdx.x;
    __shared__ float xs[FIN];
    __shared__ float ags[128];
    __shared__ float hbuf[C];
    xs[t] = x[(size_t)n * FIN + t];
    xs[t + 64] = x[(size_t)n * FIN + 64 + t];
    ags[t] = aggEA[(size_t)n * 128 + t];
    ags[t + 64] = aggEA[(size_t)n * 128 + 64 + t];
    __syncthreads();

    float acc = accV[(size_t)n * C + t] + bskip[t];
#pragma unroll 8
    for (int f = 0; f < FIN; ++f) acc += xs[f] * Wskip[f * C + t];
#pragma unroll 8
    for (int idx = 0; idx < 128; ++idx) {
        int h = idx >> 5, f = idx & 31;
        acc += ags[idx] * We[f * HC + h * C + t];
    }
    acc = fmaxf(acc, 0.f);
    acc = (acc - rmean[t]) / sqrtf(rvar[t] + BN_EPS) * gamma[t] + beta[t];
    hbuf[t] = acc;
    __syncthreads();

    if (t < NCLS) {
        float o = bc[t];
#pragma unroll 8
        for (int c2 = 0; c2 < C; ++c2) o += hbuf[c2] * Wc[c2 * NCLS + t];
        out[(size_t)n * NCLS + t] = o;
    }
}

extern "C" void kernel_launch(void* const* d_in, const int* in_sizes, int n_in,
                              void* d_out, int out_size, void* d_ws, size_t ws_size,
                              hipStream_t stream)
{
    const float* x     = (const float*)d_in[0];
    const int*   ei    = (const int*)d_in[1];
    const float* ea    = (const float*)d_in[2];
    const float* Wq    = (const float*)d_in[3];
    const float* bq    = (const float*)d_in[4];
    const float* Wk    = (const float*)d_in[5];
    const float* bk    = (const float*)d_in[6];
    const float* Wv    = (const float*)d_in[7];
    const float* bv    = (const float*)d_in[8];
    const float* We    = (const float*)d_in[9];
    const float* Wskip = (const float*)d_in[10];
    const float* bskip = (const float*)d_in[11];
    const float* gamma = (const float*)d_in[12];
    const float* beta  = (const float*)d_in[13];
    const float* rmean = (const float*)d_in[14];
    const float* rvar  = (const float*)d_in[15];
    const float* Wc    = (const float*)d_in[16];
    const float* bc    = (const float*)d_in[17];
    float* out = (float*)d_out;

    const int N = in_sizes[0] / FIN;
    const int E = in_sizes[2] / FE;
    const int* srcp = ei;
    const int* dstp = ei + E;

    char* w = (char*)d_ws;
    size_t off = 0;
    auto alloc = [&](size_t bytes) { void* p = w + off; off += (bytes + 255) & ~255ull; return p; };
    bf16*  qb    = (bf16*)alloc((size_t)N * HC * sizeof(bf16));
    bf16*  kb    = (bf16*)alloc((size_t)N * HC * sizeof(bf16));
    bf16*  vb    = (bf16*)alloc((size_t)N * HC * sizeof(bf16));
    float* qWe   = (float*)alloc((size_t)N * 128 * sizeof(float));
    float* ex    = (float*)alloc((size_t)E * H * sizeof(float));
    float* denom = (float*)alloc((size_t)N * H * sizeof(float));
    float* accV  = (float*)alloc((size_t)N * C * sizeof(float));
    float* aggEA = (float*)alloc((size_t)N * 128 * sizeof(float));
    short* Wt    = (short*)alloc((size_t)WCOLS * FIN * sizeof(short));
    float* bias  = (float*)alloc((size_t)WCOLS * sizeof(float));

    hipMemsetAsync(denom, 0, (size_t)N * H * sizeof(float), stream);
    hipMemsetAsync(accV,  0, (size_t)N * C * sizeof(float), stream);
    hipMemsetAsync(aggEA, 0, (size_t)N * 128 * sizeof(float), stream);

    pack_w_kernel<<<WCOLS, 128, 0, stream>>>(Wq, Wk, Wv, We, bq, bk, bv, Wt, bias);
    qkv_mfma_kernel<<<(N + 15) / 16, 256, 0, stream>>>(x, Wt, bias, qb, kb, vb, qWe, N);
    score_kernel<<<(E + 3) / 4, 256, 0, stream>>>(srcp, dstp, ea, qWe, qb, kb, ex, denom, E);
    msg_kernel<<<(E + 3) / 4, 256, 0, stream>>>(srcp, dstp, ea, vb, ex, denom, accV, aggEA, E);
    final_kernel<<<N, 64, 0, stream>>>(x, accV, aggEA, We, Wskip, bskip, gamma, beta, rmean, rvar, Wc, bc, out, N);
}

// Round 4
// 513.850 us; speedup vs baseline: 2.4441x; 1.3121x over previous
//
#include <hip/hip_runtime.h>
#include <hip/hip_bf16.h>

#define H 4
#define C 64
#define HC 256
#define FIN 128
#define FE 32
#define NCLS 16
#define BN_EPS 1e-5f
#define WCOLS 896   // 256 q | 256 k | 256 v | 128 qWe

typedef __hip_bfloat16 bf16;
typedef __attribute__((ext_vector_type(8))) short short8v;
typedef __attribute__((ext_vector_type(4))) float floatx4;

__device__ __forceinline__ float b2f(bf16 v) { return __bfloat162float(v); }
__device__ __forceinline__ short f2bs(float f) {
    bf16 h = __float2bfloat16(f);
    return *reinterpret_cast<short*>(&h);
}

// ------- pack weights: Wt[col][k] bf16 + bias[896] -------
__global__ __launch_bounds__(128) void pack_w_kernel(
    const float* __restrict__ Wq, const float* __restrict__ Wk, const float* __restrict__ Wv,
    const float* __restrict__ We,
    const float* __restrict__ bq, const float* __restrict__ bk, const float* __restrict__ bv,
    short* __restrict__ Wt, float* __restrict__ bias)
{
    const int col = blockIdx.x;      // 0..895
    const int t = threadIdx.x;       // 0..127 = k index
    float val;
    if (col < 256)      val = Wq[t * HC + col];
    else if (col < 512) val = Wk[t * HC + col - 256];
    else if (col < 768) val = Wv[t * HC + col - 512];
    else {
        int j = col - 768, h = j >> 5, f = j & 31;
        float acc = 0.f;
#pragma unroll 8
        for (int c = 0; c < C; ++c) acc += Wq[t * HC + h * C + c] * We[f * HC + h * C + c];
        val = acc;
    }
    Wt[(size_t)col * FIN + t] = f2bs(val);
    if (t == 0) {
        float b;
        if (col < 256)      b = bq[col];
        else if (col < 512) b = bk[col - 256];
        else if (col < 768) b = bv[col - 512];
        else {
            int j = col - 768, h = j >> 5, f = j & 31;
            float acc = 0.f;
            for (int c = 0; c < C; ++c) acc += bq[h * C + c] * We[f * HC + h * C + c];
            b = acc;
        }
        bias[col] = b;
    }
}

// ------- MFMA: [N,128] x Wt[896,128]^T -> q,k,v,qWe (all bf16) -------
__global__ __launch_bounds__(256) void qkv_mfma_kernel(
    const float* __restrict__ x, const short* __restrict__ Wt,
    const float* __restrict__ bias,
    bf16* __restrict__ q, bf16* __restrict__ k, bf16* __restrict__ v,
    bf16* __restrict__ qWe, int N)
{
    const int wid = threadIdx.x >> 6;
    const int lane = threadIdx.x & 63;
    const int n0 = blockIdx.x * 16;
    const int arow = lane & 15, agrp = lane >> 4;

    int nA = n0 + arow; if (nA >= N) nA = N - 1;
    const float* xrow = x + (size_t)nA * FIN + agrp * 8;
    short8v afrag[4];
#pragma unroll
    for (int ks = 0; ks < 4; ++ks) {
        floatx4 x0 = *(const floatx4*)(xrow + ks * 32);
        floatx4 x1 = *(const floatx4*)(xrow + ks * 32 + 4);
        short8v a;
        a[0] = f2bs(x0[0]); a[1] = f2bs(x0[1]); a[2] = f2bs(x0[2]); a[3] = f2bs(x0[3]);
        a[4] = f2bs(x1[0]); a[5] = f2bs(x1[1]); a[6] = f2bs(x1[2]); a[7] = f2bs(x1[3]);
        afrag[ks] = a;
    }

    for (int ct = wid; ct < WCOLS / 16; ct += 4) {
        const int col0 = ct * 16;
        const int col = col0 + arow;
        floatx4 acc = {0.f, 0.f, 0.f, 0.f};
        const short* wp = Wt + (size_t)col * FIN + agrp * 8;
#pragma unroll
        for (int ks = 0; ks < 4; ++ks) {
            short8v b = *(const short8v*)(wp + ks * 32);
            acc = __builtin_amdgcn_mfma_f32_16x16x32_bf16(afrag[ks], b, acc, 0, 0, 0);
        }
        const float bb = bias[col];
        const int rbase = n0 + agrp * 4;
#pragma unroll
        for (int r = 0; r < 4; ++r) {
            const int n = rbase + r;
            if (n >= N) continue;
            const float val = acc[r] + bb;
            if (col0 < 256)      q[(size_t)n * HC + col]          = __float2bfloat16(val);
            else if (col0 < 512) k[(size_t)n * HC + col - 256]    = __float2bfloat16(val);
            else if (col0 < 768) v[(size_t)n * HC + col - 512]    = __float2bfloat16(val);
            else                 qWe[(size_t)n * 128 + col - 768] = __float2bfloat16(val);
        }
    }
}

// ------- CSR build: histogram -------
__global__ __launch_bounds__(256) void hist_kernel(
    const int* __restrict__ dst, int* __restrict__ deg, int E)
{
    const int i = blockIdx.x * 256 + threadIdx.x;
    if (i < E) atomicAdd(&deg[dst[i]], 1);
}

// ------- CSR build: exclusive prefix scan (single block, 1024 threads) -------
__global__ __launch_bounds__(1024) void scan_kernel(
    const int* __restrict__ deg, int* __restrict__ rowptr, int N)
{
    const int tid = threadIdx.x;
    const int chunk = (N + 1023) >> 10;
    const int base = tid * chunk;
    int s = 0;
    for (int i = 0; i < chunk; ++i) {
        int idx = base + i;
        if (idx < N) s += deg[idx];
    }
    __shared__ int part[1024];
    part[tid] = s;
    __syncthreads();
    for (int off = 1; off < 1024; off <<= 1) {
        int vv = (tid >= off) ? part[tid - off] : 0;
        __syncthreads();
        part[tid] += vv;
        __syncthreads();
    }
    int run = part[tid] - s;   // exclusive base of this chunk
    for (int i = 0; i < chunk; ++i) {
        int idx = base + i;
        if (idx < N) { rowptr[idx] = run; run += deg[idx]; }
        else if (idx == N) rowptr[N] = run;
    }
}

// ------- CSR build: scatter src + ea(bf16) into dst-sorted order -------
__global__ __launch_bounds__(256) void scatter_kernel(
    const int* __restrict__ src, const int* __restrict__ dst,
    const float* __restrict__ ea, const int* __restrict__ rowptr,
    int* __restrict__ cnt2, int* __restrict__ srcs, bf16* __restrict__ ea_s, int E)
{
    const int e = (blockIdx.x * 256 + threadIdx.x) >> 5;
    const int l = threadIdx.x & 31;
    if (e >= E) return;
    const int d = dst[e];
    int pos = 0;
    if (l == 0) pos = rowptr[d] + atomicAdd(&cnt2[d], 1);
    pos = __shfl(pos, 0, 32);
    if (l == 0) srcs[pos] = src[e];
    ea_s[(size_t)pos * FE + l] = __float2bfloat16(ea[(size_t)e * FE + l]);
}

// ------- fused per-node aggregation: score+softmax+message, no atomics -------
__global__ __launch_bounds__(256) void node_agg_kernel(
    const int* __restrict__ srcs, const int* __restrict__ rowptr,
    const bf16* __restrict__ ea_s,
    const bf16* __restrict__ q, const bf16* __restrict__ k, const bf16* __restrict__ v,
    const bf16* __restrict__ qWe,
    float* __restrict__ accV, float* __restrict__ aggEA, int N)
{
    const int w = threadIdx.x >> 6;
    const int lane = threadIdx.x & 63;
    const int d = blockIdx.x * 4 + w;
    if (d >= N) return;
    const int lf = lane & 31;

    float qv0 = b2f(q[(size_t)d * HC + 0 * C + lane]);
    float qv1 = b2f(q[(size_t)d * HC + 1 * C + lane]);
    float qv2 = b2f(q[(size_t)d * HC + 2 * C + lane]);
    float qv3 = b2f(q[(size_t)d * HC + 3 * C + lane]);
    float qw0 = 0.f, qw1 = 0.f, qw2 = 0.f, qw3 = 0.f;
    if (lane < 32) {
        qw0 = b2f(qWe[(size_t)d * 128 + 0 * FE + lf]);
        qw1 = b2f(qWe[(size_t)d * 128 + 1 * FE + lf]);
        qw2 = b2f(qWe[(size_t)d * 128 + 2 * FE + lf]);
        qw3 = b2f(qWe[(size_t)d * 128 + 3 * FE + lf]);
    }

    float den0 = 0.f, den1 = 0.f, den2 = 0.f, den3 = 0.f;
    float acc0 = 0.f, acc1 = 0.f, acc2 = 0.f, acc3 = 0.f;
    float agg0 = 0.f, agg1 = 0.f, agg2 = 0.f, agg3 = 0.f;

    const int end = rowptr[d + 1];
    for (int i = rowptr[d]; i < end; ++i) {
        const int s = srcs[i];
        const float eav = (lane < 32) ? b2f(ea_s[(size_t)i * FE + lf]) : 0.f;
        const bf16* krow = k + (size_t)s * HC;
        float p0 = qv0 * b2f(krow[0 * C + lane]) + qw0 * eav;
        float p1 = qv1 * b2f(krow[1 * C + lane]) + qw1 * eav;
        float p2 = qv2 * b2f(krow[2 * C + lane]) + qw2 * eav;
        float p3 = qv3 * b2f(krow[3 * C + lane]) + qw3 * eav;
#pragma unroll
        for (int off = 32; off >= 1; off >>= 1) {
            p0 += __shfl_xor(p0, off, 64);
            p1 += __shfl_xor(p1, off, 64);
            p2 += __shfl_xor(p2, off, 64);
            p3 += __shfl_xor(p3, off, 64);
        }
        const float e0 = expf(p0 * 0.125f);
        const float e1 = expf(p1 * 0.125f);
        const float e2 = expf(p2 * 0.125f);
        const float e3 = expf(p3 * 0.125f);
        den0 += e0; den1 += e1; den2 += e2; den3 += e3;
        const bf16* vrow = v + (size_t)s * HC;
        acc0 += e0 * b2f(vrow[0 * C + lane]);
        acc1 += e1 * b2f(vrow[1 * C + lane]);
        acc2 += e2 * b2f(vrow[2 * C + lane]);
        acc3 += e3 * b2f(vrow[3 * C + lane]);
        agg0 += e0 * eav; agg1 += e1 * eav; agg2 += e2 * eav; agg3 += e3 * eav;
    }

    const float i0 = den0 > 0.f ? 0.25f / den0 : 0.f;
    const float i1 = den1 > 0.f ? 0.25f / den1 : 0.f;
    const float i2 = den2 > 0.f ? 0.25f / den2 : 0.f;
    const float i3 = den3 > 0.f ? 0.25f / den3 : 0.f;

    accV[(size_t)d * C + lane] = acc0 * i0 + acc1 * i1 + acc2 * i2 + acc3 * i3;
    if (lane < 32) {
        aggEA[(size_t)d * 128 + 0 * FE + lf] = agg0 * i0;
        aggEA[(size_t)d * 128 + 1 * FE + lf] = agg1 * i1;
        aggEA[(size_t)d * 128 + 2 * FE + lf] = agg2 * i2;
        aggEA[(size_t)d * 128 + 3 * FE + lf] = agg3 * i3;
    }
}

// ------- final: + aggEA@We + skip GEMM + ReLU + BN + classifier (4 waves/block) -------
__global__ __launch_bounds__(256) void final_kernel(
    const float* __restrict__ x, const float* __restrict__ accV,
    const float* __restrict__ aggEA, const float* __restrict__ We,
    const float* __restrict__ Wskip, const float* __restrict__ bskip,
    const float* __restrict__ gamma, const float* __restrict__ beta,
    const float* __restrict__ rmean, const float* __restrict__ rvar,
    const float* __restrict__ Wc, const float* __restrict__ bc,
    float* __restrict__ out, int N)
{
    const int w = threadIdx.x >> 6;
    const int t = threadIdx.x & 63;
    const int n = blockIdx.x * 4 + w;
    __shared__ float xs[4][FIN];
    __shared__ float ags[4][128];
    __shared__ float hbuf[4][C];
    if (n < N) {
        xs[w][t]        = x[(size_t)n * FIN + t];
        xs[w][t + 64]   = x[(size_t)n * FIN + 64 + t];
        ags[w][t]       = aggEA[(size_t)n * 128 + t];
        ags[w][t + 64]  = aggEA[(size_t)n * 128 + 64 + t];
    }
    __syncthreads();
    if (n < N) {
        float acc = accV[(size_t)n * C + t] + bskip[t];
#pragma unroll 8
        for (int f = 0; f < FIN; ++f) acc += xs[w][f] * Wskip[f * C + t];
#pragma unroll 8
        for (int idx = 0; idx < 128; ++idx) {
            int h = idx >> 5, f = idx & 31;
            acc += ags[w][idx] * We[f * HC + h * C + t];
        }
        acc = fmaxf(acc, 0.f);
        acc = (acc - rmean[t]) / sqrtf(rvar[t] + BN_EPS) * gamma[t] + beta[t];
        hbuf[w][t] = acc;
    }
    __syncthreads();
    if (n < N && t < NCLS) {
        float o = bc[t];
#pragma unroll 8
        for (int c2 = 0; c2 < C; ++c2) o += hbuf[w][c2] * Wc[c2 * NCLS + t];
        out[(size_t)n * NCLS + t] = o;
    }
}

extern "C" void kernel_launch(void* const* d_in, const int* in_sizes, int n_in,
                              void* d_out, int out_size, void* d_ws, size_t ws_size,
                              hipStream_t stream)
{
    const float* x     = (const float*)d_in[0];
    const int*   ei    = (const int*)d_in[1];
    const float* ea    = (const float*)d_in[2];
    const float* Wq    = (const float*)d_in[3];
    const float* bq    = (const float*)d_in[4];
    const float* Wk    = (const float*)d_in[5];
    const float* bk    = (const float*)d_in[6];
    const float* Wv    = (const float*)d_in[7];
    const float* bv    = (const float*)d_in[8];
    const float* We    = (const float*)d_in[9];
    const float* Wskip = (const float*)d_in[10];
    const float* bskip = (const float*)d_in[11];
    const float* gamma = (const float*)d_in[12];
    const float* beta  = (const float*)d_in[13];
    const float* rmean = (const float*)d_in[14];
    const float* rvar  = (const float*)d_in[15];
    const float* Wc    = (const float*)d_in[16];
    const float* bc    = (const float*)d_in[17];
    float* out = (float*)d_out;

    const int N = in_sizes[0] / FIN;
    const int E = in_sizes[2] / FE;
    const int* srcp = ei;
    const int* dstp = ei + E;

    char* w = (char*)d_ws;
    size_t off = 0;
    auto alloc = [&](size_t bytes) { void* p = w + off; off += (bytes + 255) & ~255ull; return p; };
    bf16*  qb     = (bf16*)alloc((size_t)N * HC * sizeof(bf16));
    bf16*  kb     = (bf16*)alloc((size_t)N * HC * sizeof(bf16));
    bf16*  vb     = (bf16*)alloc((size_t)N * HC * sizeof(bf16));
    bf16*  qWe    = (bf16*)alloc((size_t)N * 128 * sizeof(bf16));
    int*   deg    = (int*)alloc((size_t)N * sizeof(int));
    int*   rowptr = (int*)alloc((size_t)(N + 1) * sizeof(int));
    int*   cnt2   = (int*)alloc((size_t)N * sizeof(int));
    int*   srcs   = (int*)alloc((size_t)E * sizeof(int));
    bf16*  ea_s   = (bf16*)alloc((size_t)E * FE * sizeof(bf16));
    float* accV   = (float*)alloc((size_t)N * C * sizeof(float));
    float* aggEA  = (float*)alloc((size_t)N * 128 * sizeof(float));
    short* Wt     = (short*)alloc((size_t)WCOLS * FIN * sizeof(short));
    float* bias   = (float*)alloc((size_t)WCOLS * sizeof(float));

    hipMemsetAsync(deg,  0, (size_t)N * sizeof(int), stream);
    hipMemsetAsync(cnt2, 0, (size_t)N * sizeof(int), stream);

    pack_w_kernel<<<WCOLS, 128, 0, stream>>>(Wq, Wk, Wv, We, bq, bk, bv, Wt, bias);
    qkv_mfma_kernel<<<(N + 15) / 16, 256, 0, stream>>>(x, Wt, bias, qb, kb, vb, qWe, N);
    hist_kernel<<<(E + 255) / 256, 256, 0, stream>>>(dstp, deg, E);
    scan_kernel<<<1, 1024, 0, stream>>>(deg, rowptr, N);
    scatter_kernel<<<(E * 32 + 255) / 256, 256, 0, stream>>>(srcp, dstp, ea, rowptr, cnt2, srcs, ea_s, E);
    node_agg_kernel<<<(N + 3) / 4, 256, 0, stream>>>(srcs, rowptr, ea_s, qb, kb, vb, qWe, accV, aggEA, N);
    final_kernel<<<(N + 3) / 4, 256, 0, stream>>>(x, accV, aggEA, We, Wskip, bskip, gamma, beta, rmean, rvar, Wc, bc, out, N);
}

// Round 5
// 413.576 us; speedup vs baseline: 3.0367x; 1.2425x over previous
//
#include <hip/hip_runtime.h>
#include <hip/hip_bf16.h>

#define H 4
#define C 64
#define HC 256
#define FIN 128
#define FE 32
#define NCLS 16
#define BN_EPS 1e-5f
#define WCOLS 960   // 256 q | 256 k | 256 v | 128 qWe | 64 skip

typedef __hip_bfloat16 bf16;
typedef __attribute__((ext_vector_type(8))) short short8v;
typedef __attribute__((ext_vector_type(4))) float floatx4;

__device__ __forceinline__ float b2f(bf16 v) { return __bfloat162float(v); }
__device__ __forceinline__ short f2bs(float f) {
    bf16 h = __float2bfloat16(f);
    return *reinterpret_cast<short*>(&h);
}

// ------- pack: Wt[960][128] bf16 + bias[960] + Wet[64][128] + Wct[16][64] + BN scale/shift -------
__global__ __launch_bounds__(128) void pack_w_kernel(
    const float* __restrict__ Wq, const float* __restrict__ Wk, const float* __restrict__ Wv,
    const float* __restrict__ We, const float* __restrict__ Wskip,
    const float* __restrict__ bq, const float* __restrict__ bk, const float* __restrict__ bv,
    const float* __restrict__ bskip,
    const float* __restrict__ gamma, const float* __restrict__ beta,
    const float* __restrict__ rmean, const float* __restrict__ rvar,
    const float* __restrict__ Wc,
    short* __restrict__ Wt, float* __restrict__ bias,
    short* __restrict__ Wet, short* __restrict__ Wct,
    float* __restrict__ scalev, float* __restrict__ shiftv)
{
    const int bid = blockIdx.x;
    const int t = threadIdx.x;       // 0..127
    if (bid < WCOLS) {
        const int col = bid;
        float val, b = 0.f;
        if (col < 256)      { val = Wq[t * HC + col]; b = bq[col]; }
        else if (col < 512) { val = Wk[t * HC + col - 256]; b = bk[col - 256]; }
        else if (col < 768) { val = Wv[t * HC + col - 512]; b = bv[col - 512]; }
        else if (col < 896) {
            int j = col - 768, h = j >> 5, f = j & 31;
            float acc = 0.f;
#pragma unroll 8
            for (int c = 0; c < C; ++c) acc += Wq[t * HC + h * C + c] * We[f * HC + h * C + c];
            val = acc;
            acc = 0.f;
            for (int c = 0; c < C; ++c) acc += bq[h * C + c] * We[f * HC + h * C + c];
            b = acc;
        }
        else { int c2 = col - 896; val = Wskip[t * C + c2]; b = bskip[c2]; }
        Wt[(size_t)col * FIN + t] = f2bs(val);
        if (t == 0) bias[col] = b;
    } else if (bid < WCOLS + 64) {
        // Wet[c][k]: k = h*32+f -> We[f*256 + h*64 + c]
        const int c2 = bid - WCOLS;
        const int f = t & 31, h = t >> 5;
        Wet[(size_t)c2 * FIN + t] = f2bs(We[f * HC + h * C + c2]);
    } else if (bid < WCOLS + 64 + NCLS) {
        const int cls = bid - WCOLS - 64;
        if (t < C) Wct[(size_t)cls * C + t] = f2bs(Wc[t * NCLS + cls]);
    } else {
        if (t < C) {
            float inv = rsqrtf(rvar[t] + BN_EPS);
            float sc = gamma[t] * inv;
            scalev[t] = sc;
            shiftv[t] = beta[t] - rmean[t] * sc;
        }
    }
}

// ------- MFMA: [N,128] x Wt[960,128]^T -> q,k,v,qWe,skip (all bf16) -------
__global__ __launch_bounds__(256) void qkv_mfma_kernel(
    const float* __restrict__ x, const short* __restrict__ Wt,
    const float* __restrict__ bias,
    bf16* __restrict__ q, bf16* __restrict__ k, bf16* __restrict__ v,
    bf16* __restrict__ qWe, bf16* __restrict__ skip, int N)
{
    const int wid = threadIdx.x >> 6;
    const int lane = threadIdx.x & 63;
    const int n0 = blockIdx.x * 16;
    const int arow = lane & 15, agrp = lane >> 4;

    int nA = n0 + arow; if (nA >= N) nA = N - 1;
    const float* xrow = x + (size_t)nA * FIN + agrp * 8;
    short8v afrag[4];
#pragma unroll
    for (int ks = 0; ks < 4; ++ks) {
        floatx4 x0 = *(const floatx4*)(xrow + ks * 32);
        floatx4 x1 = *(const floatx4*)(xrow + ks * 32 + 4);
        short8v a;
        a[0] = f2bs(x0[0]); a[1] = f2bs(x0[1]); a[2] = f2bs(x0[2]); a[3] = f2bs(x0[3]);
        a[4] = f2bs(x1[0]); a[5] = f2bs(x1[1]); a[6] = f2bs(x1[2]); a[7] = f2bs(x1[3]);
        afrag[ks] = a;
    }

    for (int ct = wid; ct < WCOLS / 16; ct += 4) {
        const int col0 = ct * 16;
        const int col = col0 + arow;
        floatx4 acc = {0.f, 0.f, 0.f, 0.f};
        const short* wp = Wt + (size_t)col * FIN + agrp * 8;
#pragma unroll
        for (int ks = 0; ks < 4; ++ks) {
            short8v b = *(const short8v*)(wp + ks * 32);
            acc = __builtin_amdgcn_mfma_f32_16x16x32_bf16(afrag[ks], b, acc, 0, 0, 0);
        }
        const float bb = bias[col];
        const int rbase = n0 + agrp * 4;
#pragma unroll
        for (int r = 0; r < 4; ++r) {
            const int n = rbase + r;
            if (n >= N) continue;
            const float val = acc[r] + bb;
            if (col0 < 256)      q[(size_t)n * HC + col]          = __float2bfloat16(val);
            else if (col0 < 512) k[(size_t)n * HC + col - 256]    = __float2bfloat16(val);
            else if (col0 < 768) v[(size_t)n * HC + col - 512]    = __float2bfloat16(val);
            else if (col0 < 896) qWe[(size_t)n * 128 + col - 768] = __float2bfloat16(val);
            else                 skip[(size_t)n * C + col - 896]  = __float2bfloat16(val);
        }
    }
}

// ------- CSR build -------
__global__ __launch_bounds__(256) void hist_kernel(
    const int* __restrict__ dst, int* __restrict__ deg, int E)
{
    const int i = blockIdx.x * 256 + threadIdx.x;
    if (i < E) atomicAdd(&deg[dst[i]], 1);
}

__global__ __launch_bounds__(1024) void scan_kernel(
    const int* __restrict__ deg, int* __restrict__ rowptr, int N)
{
    const int tid = threadIdx.x;
    const int chunk = (N + 1023) >> 10;
    const int base = tid * chunk;
    int s = 0;
    for (int i = 0; i < chunk; ++i) {
        int idx = base + i;
        if (idx < N) s += deg[idx];
    }
    __shared__ int part[1024];
    part[tid] = s;
    __syncthreads();
    for (int off = 1; off < 1024; off <<= 1) {
        int vv = (tid >= off) ? part[tid - off] : 0;
        __syncthreads();
        part[tid] += vv;
        __syncthreads();
    }
    int run = part[tid] - s;
    for (int i = 0; i < chunk; ++i) {
        int idx = base + i;
        if (idx < N) { rowptr[idx] = run; run += deg[idx]; }
        else if (idx == N) rowptr[N] = run;
    }
}

__global__ __launch_bounds__(256) void scatter_kernel(
    const int* __restrict__ src, const int* __restrict__ dst,
    const float* __restrict__ ea, const int* __restrict__ rowptr,
    int* __restrict__ cnt2, int* __restrict__ srcs, bf16* __restrict__ ea_s, int E)
{
    const int e = (blockIdx.x * 256 + threadIdx.x) >> 5;
    const int l = threadIdx.x & 31;
    if (e >= E) return;
    const int d = dst[e];
    int pos = 0;
    if (l == 0) pos = rowptr[d] + atomicAdd(&cnt2[d], 1);
    pos = __shfl(pos, 0, 32);
    if (l == 0) srcs[pos] = src[e];
    ea_s[(size_t)pos * FE + l] = __float2bfloat16(ea[(size_t)e * FE + l]);
}

// ------- fused per-node aggregation (gather, no atomics) -------
__global__ __launch_bounds__(256) void node_agg_kernel(
    const int* __restrict__ srcs, const int* __restrict__ rowptr,
    const bf16* __restrict__ ea_s,
    const bf16* __restrict__ q, const bf16* __restrict__ k, const bf16* __restrict__ v,
    const bf16* __restrict__ qWe,
    float* __restrict__ accV, bf16* __restrict__ aggEA, int N)
{
    const int w = threadIdx.x >> 6;
    const int lane = threadIdx.x & 63;
    const int d = blockIdx.x * 4 + w;
    if (d >= N) return;
    const int lf = lane & 31;

    float qv0 = b2f(q[(size_t)d * HC + 0 * C + lane]);
    float qv1 = b2f(q[(size_t)d * HC + 1 * C + lane]);
    float qv2 = b2f(q[(size_t)d * HC + 2 * C + lane]);
    float qv3 = b2f(q[(size_t)d * HC + 3 * C + lane]);
    float qw0 = 0.f, qw1 = 0.f, qw2 = 0.f, qw3 = 0.f;
    if (lane < 32) {
        qw0 = b2f(qWe[(size_t)d * 128 + 0 * FE + lf]);
        qw1 = b2f(qWe[(size_t)d * 128 + 1 * FE + lf]);
        qw2 = b2f(qWe[(size_t)d * 128 + 2 * FE + lf]);
        qw3 = b2f(qWe[(size_t)d * 128 + 3 * FE + lf]);
    }

    float den0 = 0.f, den1 = 0.f, den2 = 0.f, den3 = 0.f;
    float acc0 = 0.f, acc1 = 0.f, acc2 = 0.f, acc3 = 0.f;
    float agg0 = 0.f, agg1 = 0.f, agg2 = 0.f, agg3 = 0.f;

    const int end = rowptr[d + 1];
    for (int i = rowptr[d]; i < end; ++i) {
        const int s = srcs[i];
        const float eav = (lane < 32) ? b2f(ea_s[(size_t)i * FE + lf]) : 0.f;
        const bf16* krow = k + (size_t)s * HC;
        float p0 = qv0 * b2f(krow[0 * C + lane]) + qw0 * eav;
        float p1 = qv1 * b2f(krow[1 * C + lane]) + qw1 * eav;
        float p2 = qv2 * b2f(krow[2 * C + lane]) + qw2 * eav;
        float p3 = qv3 * b2f(krow[3 * C + lane]) + qw3 * eav;
#pragma unroll
        for (int off = 32; off >= 1; off >>= 1) {
            p0 += __shfl_xor(p0, off, 64);
            p1 += __shfl_xor(p1, off, 64);
            p2 += __shfl_xor(p2, off, 64);
            p3 += __shfl_xor(p3, off, 64);
        }
        const float e0 = expf(p0 * 0.125f);
        const float e1 = expf(p1 * 0.125f);
        const float e2 = expf(p2 * 0.125f);
        const float e3 = expf(p3 * 0.125f);
        den0 += e0; den1 += e1; den2 += e2; den3 += e3;
        const bf16* vrow = v + (size_t)s * HC;
        acc0 += e0 * b2f(vrow[0 * C + lane]);
        acc1 += e1 * b2f(vrow[1 * C + lane]);
        acc2 += e2 * b2f(vrow[2 * C + lane]);
        acc3 += e3 * b2f(vrow[3 * C + lane]);
        agg0 += e0 * eav; agg1 += e1 * eav; agg2 += e2 * eav; agg3 += e3 * eav;
    }

    const float i0 = den0 > 0.f ? 0.25f / den0 : 0.f;
    const float i1 = den1 > 0.f ? 0.25f / den1 : 0.f;
    const float i2 = den2 > 0.f ? 0.25f / den2 : 0.f;
    const float i3 = den3 > 0.f ? 0.25f / den3 : 0.f;

    accV[(size_t)d * C + lane] = acc0 * i0 + acc1 * i1 + acc2 * i2 + acc3 * i3;
    if (lane < 32) {
        aggEA[(size_t)d * 128 + 0 * FE + lf] = __float2bfloat16(agg0 * i0);
        aggEA[(size_t)d * 128 + 1 * FE + lf] = __float2bfloat16(agg1 * i1);
        aggEA[(size_t)d * 128 + 2 * FE + lf] = __float2bfloat16(agg2 * i2);
        aggEA[(size_t)d * 128 + 3 * FE + lf] = __float2bfloat16(agg3 * i3);
    }
}

// ------- final: MFMA aggEA@Wet + epilogue + MFMA classifier -------
__global__ __launch_bounds__(256) void final_kernel(
    const bf16* __restrict__ aggEA, const float* __restrict__ accV,
    const bf16* __restrict__ skip,
    const short* __restrict__ Wet, const short* __restrict__ Wct,
    const float* __restrict__ scalev, const float* __restrict__ shiftv,
    const float* __restrict__ bc,
    float* __restrict__ out, int N)
{
    const int wid = threadIdx.x >> 6;
    const int lane = threadIdx.x & 63;
    const int n0 = blockIdx.x * 16;
    const int arow = lane & 15, agrp = lane >> 4;
    __shared__ short hs[16][72];   // bf16 h-tile, padded

    int nA = n0 + arow; if (nA >= N) nA = N - 1;
    const short* ap = (const short*)aggEA + (size_t)nA * 128 + agrp * 8;
    const int c0 = wid * 16;
    const int col = c0 + arow;
    const short* wp = Wet + (size_t)col * FIN + agrp * 8;
    floatx4 acc = {0.f, 0.f, 0.f, 0.f};
#pragma unroll
    for (int ks = 0; ks < 4; ++ks) {
        short8v a = *(const short8v*)(ap + ks * 32);
        short8v b = *(const short8v*)(wp + ks * 32);
        acc = __builtin_amdgcn_mfma_f32_16x16x32_bf16(a, b, acc, 0, 0, 0);
    }
    const float sc = scalev[col], sh = shiftv[col];
#pragma unroll
    for (int r = 0; r < 4; ++r) {
        const int row = agrp * 4 + r;
        int n = n0 + row; int nc = (n < N) ? n : (N - 1);
        float z = acc[r] + accV[(size_t)nc * C + col] + b2f(skip[(size_t)nc * C + col]);
        z = fmaxf(z, 0.f);
        z = z * sc + sh;
        hs[row][col] = f2bs(z);
    }
    __syncthreads();

    if (wid == 0) {
        short8v ah[2], bh[2];
#pragma unroll
        for (int ks = 0; ks < 2; ++ks) {
#pragma unroll
            for (int j = 0; j < 8; ++j) ah[ks][j] = hs[arow][ks * 32 + agrp * 8 + j];
            bh[ks] = *(const short8v*)(Wct + (size_t)arow * C + ks * 32 + agrp * 8);
        }
        floatx4 co = {0.f, 0.f, 0.f, 0.f};
        co = __builtin_amdgcn_mfma_f32_16x16x32_bf16(ah[0], bh[0], co, 0, 0, 0);
        co = __builtin_amdgcn_mfma_f32_16x16x32_bf16(ah[1], bh[1], co, 0, 0, 0);
        const float bcv = bc[arow];
#pragma unroll
        for (int r = 0; r < 4; ++r) {
            const int n = n0 + agrp * 4 + r;
            if (n < N) out[(size_t)n * NCLS + arow] = co[r] + bcv;
        }
    }
}

extern "C" void kernel_launch(void* const* d_in, const int* in_sizes, int n_in,
                              void* d_out, int out_size, void* d_ws, size_t ws_size,
                              hipStream_t stream)
{
    const float* x     = (const float*)d_in[0];
    const int*   ei    = (const int*)d_in[1];
    const float* ea    = (const float*)d_in[2];
    const float* Wq    = (const float*)d_in[3];
    const float* bq    = (const float*)d_in[4];
    const float* Wk    = (const float*)d_in[5];
    const float* bk    = (const float*)d_in[6];
    const float* Wv    = (const float*)d_in[7];
    const float* bv    = (const float*)d_in[8];
    const float* We    = (const float*)d_in[9];
    const float* Wskip = (const float*)d_in[10];
    const float* bskip = (const float*)d_in[11];
    const float* gamma = (const float*)d_in[12];
    const float* beta  = (const float*)d_in[13];
    const float* rmean = (const float*)d_in[14];
    const float* rvar  = (const float*)d_in[15];
    const float* Wc    = (const float*)d_in[16];
    const float* bc    = (const float*)d_in[17];
    float* out = (float*)d_out;

    const int N = in_sizes[0] / FIN;
    const int E = in_sizes[2] / FE;
    const int* srcp = ei;
    const int* dstp = ei + E;

    char* w = (char*)d_ws;
    size_t off = 0;
    auto alloc = [&](size_t bytes) { void* p = w + off; off += (bytes + 255) & ~255ull; return p; };
    bf16*  qb     = (bf16*)alloc((size_t)N * HC * sizeof(bf16));
    bf16*  kb     = (bf16*)alloc((size_t)N * HC * sizeof(bf16));
    bf16*  vb     = (bf16*)alloc((size_t)N * HC * sizeof(bf16));
    bf16*  qWe    = (bf16*)alloc((size_t)N * 128 * sizeof(bf16));
    bf16*  skip   = (bf16*)alloc((size_t)N * C * sizeof(bf16));
    int*   deg    = (int*)alloc((size_t)N * sizeof(int));
    int*   rowptr = (int*)alloc((size_t)(N + 1) * sizeof(int));
    int*   cnt2   = (int*)alloc((size_t)N * sizeof(int));
    int*   srcs   = (int*)alloc((size_t)E * sizeof(int));
    bf16*  ea_s   = (bf16*)alloc((size_t)E * FE * sizeof(bf16));
    float* accV   = (float*)alloc((size_t)N * C * sizeof(float));
    bf16*  aggEA  = (bf16*)alloc((size_t)N * 128 * sizeof(bf16));
    short* Wt     = (short*)alloc((size_t)WCOLS * FIN * sizeof(short));
    float* bias   = (float*)alloc((size_t)WCOLS * sizeof(float));
    short* Wet    = (short*)alloc((size_t)C * FIN * sizeof(short));
    short* Wct    = (short*)alloc((size_t)NCLS * C * sizeof(short));
    float* scalev = (float*)alloc((size_t)C * sizeof(float));
    float* shiftv = (float*)alloc((size_t)C * sizeof(float));

    hipMemsetAsync(deg,  0, (size_t)N * sizeof(int), stream);
    hipMemsetAsync(cnt2, 0, (size_t)N * sizeof(int), stream);

    pack_w_kernel<<<WCOLS + 64 + NCLS + 1, 128, 0, stream>>>(
        Wq, Wk, Wv, We, Wskip, bq, bk, bv, bskip, gamma, beta, rmean, rvar, Wc,
        Wt, bias, Wet, Wct, scalev, shiftv);
    qkv_mfma_kernel<<<(N + 15) / 16, 256, 0, stream>>>(x, Wt, bias, qb, kb, vb, qWe, skip, N);
    hist_kernel<<<(E + 255) / 256, 256, 0, stream>>>(dstp, deg, E);
    scan_kernel<<<1, 1024, 0, stream>>>(deg, rowptr, N);
    scatter_kernel<<<(E * 32 + 255) / 256, 256, 0, stream>>>(srcp, dstp, ea, rowptr, cnt2, srcs, ea_s, E);
    node_agg_kernel<<<(N + 3) / 4, 256, 0, stream>>>(srcs, rowptr, ea_s, qb, kb, vb, qWe, accV, aggEA, N);
    final_kernel<<<(N + 15) / 16, 256, 0, stream>>>(aggEA, accV, skip, Wet, Wct, scalev, shiftv, bc, out, N);
}

// Round 6
// 340.446 us; speedup vs baseline: 3.6890x; 1.2148x over previous
//
#include <hip/hip_runtime.h>
#include <hip/hip_bf16.h>

#define H 4
#define C 64
#define HC 256
#define FIN 128
#define FE 32
#define NCLS 16
#define BN_EPS 1e-5f
#define WCOLS 960   // 256 q | 256 k | 256 v | 128 qWe | 64 skip

typedef __hip_bfloat16 bf16;
typedef __attribute__((ext_vector_type(8))) short short8v;
typedef __attribute__((ext_vector_type(4))) short short4v;
typedef __attribute__((ext_vector_type(2))) short short2v;
typedef __attribute__((ext_vector_type(4))) float floatx4;

__device__ __forceinline__ float b2f(bf16 v) { return __bfloat162float(v); }
__device__ __forceinline__ float bs2f(short s) {
    unsigned u = ((unsigned)(unsigned short)s) << 16;
    return __uint_as_float(u);
}
__device__ __forceinline__ short f2bs(float f) {
    bf16 h = __float2bfloat16(f);
    return *reinterpret_cast<short*>(&h);
}

// ------- pack: Wt[960][128] bf16 + bias[960] + Wet[64][128] + Wct[16][64] + BN scale/shift -------
__global__ __launch_bounds__(128) void pack_w_kernel(
    const float* __restrict__ Wq, const float* __restrict__ Wk, const float* __restrict__ Wv,
    const float* __restrict__ We, const float* __restrict__ Wskip,
    const float* __restrict__ bq, const float* __restrict__ bk, const float* __restrict__ bv,
    const float* __restrict__ bskip,
    const float* __restrict__ gamma, const float* __restrict__ beta,
    const float* __restrict__ rmean, const float* __restrict__ rvar,
    const float* __restrict__ Wc,
    short* __restrict__ Wt, float* __restrict__ bias,
    short* __restrict__ Wet, short* __restrict__ Wct,
    float* __restrict__ scalev, float* __restrict__ shiftv)
{
    const int bid = blockIdx.x;
    const int t = threadIdx.x;       // 0..127
    if (bid < WCOLS) {
        const int col = bid;
        float val, b = 0.f;
        if (col < 256)      { val = Wq[t * HC + col]; b = bq[col]; }
        else if (col < 512) { val = Wk[t * HC + col - 256]; b = bk[col - 256]; }
        else if (col < 768) { val = Wv[t * HC + col - 512]; b = bv[col - 512]; }
        else if (col < 896) {
            int j = col - 768, h = j >> 5, f = j & 31;
            float acc = 0.f;
#pragma unroll 8
            for (int c = 0; c < C; ++c) acc += Wq[t * HC + h * C + c] * We[f * HC + h * C + c];
            val = acc;
            acc = 0.f;
            for (int c = 0; c < C; ++c) acc += bq[h * C + c] * We[f * HC + h * C + c];
            b = acc;
        }
        else { int c2 = col - 896; val = Wskip[t * C + c2]; b = bskip[c2]; }
        Wt[(size_t)col * FIN + t] = f2bs(val);
        if (t == 0) bias[col] = b;
    } else if (bid < WCOLS + 64) {
        const int c2 = bid - WCOLS;
        const int f = t & 31, h = t >> 5;
        Wet[(size_t)c2 * FIN + t] = f2bs(We[f * HC + h * C + c2]);
    } else if (bid < WCOLS + 64 + NCLS) {
        const int cls = bid - WCOLS - 64;
        if (t < C) Wct[(size_t)cls * C + t] = f2bs(Wc[t * NCLS + cls]);
    } else {
        if (t < C) {
            float inv = rsqrtf(rvar[t] + BN_EPS);
            float sc = gamma[t] * inv;
            scalev[t] = sc;
            shiftv[t] = beta[t] - rmean[t] * sc;
        }
    }
}

// ------- MFMA: [N,128] x Wt[960,128]^T -> q,k,v,qWe,skip ; 32 rows/block (B reuse x2) -------
__global__ __launch_bounds__(256) void qkv_mfma_kernel(
    const float* __restrict__ x, const short* __restrict__ Wt,
    const float* __restrict__ bias,
    bf16* __restrict__ q, bf16* __restrict__ k, bf16* __restrict__ v,
    bf16* __restrict__ qWe, bf16* __restrict__ skip, int N)
{
    const int wid = threadIdx.x >> 6;
    const int lane = threadIdx.x & 63;
    const int n0 = blockIdx.x * 32;
    const int arow = lane & 15, agrp = lane >> 4;

    short8v afrag[2][4];
#pragma unroll
    for (int rt = 0; rt < 2; ++rt) {
        int nA = n0 + rt * 16 + arow; if (nA >= N) nA = N - 1;
        const float* xrow = x + (size_t)nA * FIN + agrp * 8;
#pragma unroll
        for (int ks = 0; ks < 4; ++ks) {
            floatx4 x0 = *(const floatx4*)(xrow + ks * 32);
            floatx4 x1 = *(const floatx4*)(xrow + ks * 32 + 4);
            short8v a;
            a[0] = f2bs(x0[0]); a[1] = f2bs(x0[1]); a[2] = f2bs(x0[2]); a[3] = f2bs(x0[3]);
            a[4] = f2bs(x1[0]); a[5] = f2bs(x1[1]); a[6] = f2bs(x1[2]); a[7] = f2bs(x1[3]);
            afrag[rt][ks] = a;
        }
    }

    for (int ct = wid; ct < WCOLS / 16; ct += 4) {
        const int col0 = ct * 16;
        const int col = col0 + arow;
        const short* wp = Wt + (size_t)col * FIN + agrp * 8;
        short8v bfr[4];
#pragma unroll
        for (int ks = 0; ks < 4; ++ks) bfr[ks] = *(const short8v*)(wp + ks * 32);
        floatx4 acc0 = {0.f, 0.f, 0.f, 0.f};
        floatx4 acc1 = {0.f, 0.f, 0.f, 0.f};
#pragma unroll
        for (int ks = 0; ks < 4; ++ks) {
            acc0 = __builtin_amdgcn_mfma_f32_16x16x32_bf16(afrag[0][ks], bfr[ks], acc0, 0, 0, 0);
            acc1 = __builtin_amdgcn_mfma_f32_16x16x32_bf16(afrag[1][ks], bfr[ks], acc1, 0, 0, 0);
        }
        const float bb = bias[col];
#pragma unroll
        for (int rt = 0; rt < 2; ++rt) {
            const floatx4 acc = rt ? acc1 : acc0;
            const int rbase = n0 + rt * 16 + agrp * 4;
#pragma unroll
            for (int r = 0; r < 4; ++r) {
                const int n = rbase + r;
                if (n >= N) continue;
                const float val = acc[r] + bb;
                if (col0 < 256)      q[(size_t)n * HC + col]          = __float2bfloat16(val);
                else if (col0 < 512) k[(size_t)n * HC + col - 256]    = __float2bfloat16(val);
                else if (col0 < 768) v[(size_t)n * HC + col - 512]    = __float2bfloat16(val);
                else if (col0 < 896) qWe[(size_t)n * 128 + col - 768] = __float2bfloat16(val);
                else                 skip[(size_t)n * C + col - 896]  = __float2bfloat16(val);
            }
        }
    }
}

// ------- CSR build -------
__global__ __launch_bounds__(256) void hist_kernel(
    const int* __restrict__ dst, int* __restrict__ deg, int E)
{
    const int i = blockIdx.x * 256 + threadIdx.x;
    if (i < E) atomicAdd(&deg[dst[i]], 1);
}

__global__ __launch_bounds__(1024) void scan_kernel(
    const int* __restrict__ deg, int* __restrict__ rowptr, int N)
{
    const int tid = threadIdx.x;
    const int chunk = (N + 1023) >> 10;
    const int base = tid * chunk;
    int s = 0;
    for (int i = 0; i < chunk; ++i) {
        int idx = base + i;
        if (idx < N) s += deg[idx];
    }
    __shared__ int part[1024];
    part[tid] = s;
    __syncthreads();
    for (int off = 1; off < 1024; off <<= 1) {
        int vv = (tid >= off) ? part[tid - off] : 0;
        __syncthreads();
        part[tid] += vv;
        __syncthreads();
    }
    int run = part[tid] - s;
    for (int i = 0; i < chunk; ++i) {
        int idx = base + i;
        if (idx < N) { rowptr[idx] = run; run += deg[idx]; }
        else if (idx == N) rowptr[N] = run;
    }
}

__global__ __launch_bounds__(256) void scatter_kernel(
    const int* __restrict__ src, const int* __restrict__ dst,
    const float* __restrict__ ea, const int* __restrict__ rowptr,
    int* __restrict__ cnt2, int* __restrict__ srcs, bf16* __restrict__ ea_s, int E)
{
    const int e = (blockIdx.x * 256 + threadIdx.x) >> 5;
    const int l = threadIdx.x & 31;
    if (e >= E) return;
    const int d = dst[e];
    int pos = 0;
    if (l == 0) pos = rowptr[d] + atomicAdd(&cnt2[d], 1);
    pos = __shfl(pos, 0, 32);
    if (l == 0) srcs[pos] = src[e];
    ea_s[(size_t)pos * FE + l] = __float2bfloat16(ea[(size_t)e * FE + l]);
}

// ------- fused per-node aggregation: lane = (head g, sub-lane li); 4 chan + 2 feat per lane -------
__global__ __launch_bounds__(256) void node_agg_kernel(
    const int* __restrict__ srcs, const int* __restrict__ rowptr,
    const bf16* __restrict__ ea_s,
    const bf16* __restrict__ q, const bf16* __restrict__ k, const bf16* __restrict__ v,
    const bf16* __restrict__ qWe,
    float* __restrict__ accV, bf16* __restrict__ aggEA, int N)
{
    const int w = threadIdx.x >> 6;
    const int lane = threadIdx.x & 63;
    const int d = blockIdx.x * 4 + w;
    if (d >= N) return;
    const int g = lane >> 4;     // head
    const int li = lane & 15;    // sub-lane: channels li*4..+3, features li*2..+1

    short4v qs = *(const short4v*)((const short*)q + (size_t)d * HC + g * C + li * 4);
    const float qv0 = bs2f(qs[0]), qv1 = bs2f(qs[1]), qv2 = bs2f(qs[2]), qv3 = bs2f(qs[3]);
    short2v qws = *(const short2v*)((const short*)qWe + (size_t)d * 128 + g * FE + li * 2);
    const float qw0 = bs2f(qws[0]), qw1 = bs2f(qws[1]);

    float den = 0.f;
    float a0 = 0.f, a1 = 0.f, a2 = 0.f, a3 = 0.f;
    float ag0 = 0.f, ag1 = 0.f;

    const int beg = rowptr[d], end = rowptr[d + 1];
    for (int i = beg; i < end; ++i) {
        const int s = srcs[i];
        short4v ks = *(const short4v*)((const short*)k + (size_t)s * HC + g * C + li * 4);
        short2v es = *(const short2v*)((const short*)ea_s + (size_t)i * FE + li * 2);
        const float ea0 = bs2f(es[0]), ea1 = bs2f(es[1]);
        float p = qv0 * bs2f(ks[0]) + qv1 * bs2f(ks[1])
                + qv2 * bs2f(ks[2]) + qv3 * bs2f(ks[3])
                + qw0 * ea0 + qw1 * ea1;
        p += __shfl_xor(p, 1, 64);
        p += __shfl_xor(p, 2, 64);
        p += __shfl_xor(p, 4, 64);
        p += __shfl_xor(p, 8, 64);
        const float e = exp2f(p * 0.18033688f);  // exp(p/8) = 2^(p*0.125*log2 e)
        den += e;
        short4v vs = *(const short4v*)((const short*)v + (size_t)s * HC + g * C + li * 4);
        a0 += e * bs2f(vs[0]);
        a1 += e * bs2f(vs[1]);
        a2 += e * bs2f(vs[2]);
        a3 += e * bs2f(vs[3]);
        ag0 += e * ea0; ag1 += e * ea1;
    }

    const float inv = den > 0.f ? 0.25f / den : 0.f;
    a0 *= inv; a1 *= inv; a2 *= inv; a3 *= inv;
    // head mean: sum the 4 head groups (same channels live at lanes g*16+li)
    a0 += __shfl_xor(a0, 16, 64); a0 += __shfl_xor(a0, 32, 64);
    a1 += __shfl_xor(a1, 16, 64); a1 += __shfl_xor(a1, 32, 64);
    a2 += __shfl_xor(a2, 16, 64); a2 += __shfl_xor(a2, 32, 64);
    a3 += __shfl_xor(a3, 16, 64); a3 += __shfl_xor(a3, 32, 64);
    if (g == 0) {
        floatx4 o = {a0, a1, a2, a3};
        *(floatx4*)(accV + (size_t)d * C + li * 4) = o;
    }
    short2v so;
    so[0] = f2bs(ag0 * inv);
    so[1] = f2bs(ag1 * inv);
    *(short2v*)((short*)aggEA + (size_t)d * 128 + g * FE + li * 2) = so;
}

// ------- final: MFMA aggEA@Wet + epilogue + MFMA classifier -------
__global__ __launch_bounds__(256) void final_kernel(
    const bf16* __restrict__ aggEA, const float* __restrict__ accV,
    const bf16* __restrict__ skip,
    const short* __restrict__ Wet, const short* __restrict__ Wct,
    const float* __restrict__ scalev, const float* __restrict__ shiftv,
    const float* __restrict__ bc,
    float* __restrict__ out, int N)
{
    const int wid = threadIdx.x >> 6;
    const int lane = threadIdx.x & 63;
    const int n0 = blockIdx.x * 16;
    const int arow = lane & 15, agrp = lane >> 4;
    __shared__ short hs[16][72];   // bf16 h-tile, padded

    int nA = n0 + arow; if (nA >= N) nA = N - 1;
    const short* ap = (const short*)aggEA + (size_t)nA * 128 + agrp * 8;
    const int c0 = wid * 16;
    const int col = c0 + arow;
    const short* wp = Wet + (size_t)col * FIN + agrp * 8;
    floatx4 acc = {0.f, 0.f, 0.f, 0.f};
#pragma unroll
    for (int ks = 0; ks < 4; ++ks) {
        short8v a = *(const short8v*)(ap + ks * 32);
        short8v b = *(const short8v*)(wp + ks * 32);
        acc = __builtin_amdgcn_mfma_f32_16x16x32_bf16(a, b, acc, 0, 0, 0);
    }
    const float sc = scalev[col], sh = shiftv[col];
#pragma unroll
    for (int r = 0; r < 4; ++r) {
        const int row = agrp * 4 + r;
        int n = n0 + row; int nc = (n < N) ? n : (N - 1);
        float z = acc[r] + accV[(size_t)nc * C + col] + b2f(skip[(size_t)nc * C + col]);
        z = fmaxf(z, 0.f);
        z = z * sc + sh;
        hs[row][col] = f2bs(z);
    }
    __syncthreads();

    if (wid == 0) {
        short8v ah[2], bh[2];
#pragma unroll
        for (int ks = 0; ks < 2; ++ks) {
#pragma unroll
            for (int j = 0; j < 8; ++j) ah[ks][j] = hs[arow][ks * 32 + agrp * 8 + j];
            bh[ks] = *(const short8v*)(Wct + (size_t)arow * C + ks * 32 + agrp * 8);
        }
        floatx4 co = {0.f, 0.f, 0.f, 0.f};
        co = __builtin_amdgcn_mfma_f32_16x16x32_bf16(ah[0], bh[0], co, 0, 0, 0);
        co = __builtin_amdgcn_mfma_f32_16x16x32_bf16(ah[1], bh[1], co, 0, 0, 0);
        const float bcv = bc[arow];
#pragma unroll
        for (int r = 0; r < 4; ++r) {
            const int n = n0 + agrp * 4 + r;
            if (n < N) out[(size_t)n * NCLS + arow] = co[r] + bcv;
        }
    }
}

extern "C" void kernel_launch(void* const* d_in, const int* in_sizes, int n_in,
                              void* d_out, int out_size, void* d_ws, size_t ws_size,
                              hipStream_t stream)
{
    const float* x     = (const float*)d_in[0];
    const int*   ei    = (const int*)d_in[1];
    const float* ea    = (const float*)d_in[2];
    const float* Wq    = (const float*)d_in[3];
    const float* bq    = (const float*)d_in[4];
    const float* Wk    = (const float*)d_in[5];
    const float* bk    = (const float*)d_in[6];
    const float* Wv    = (const float*)d_in[7];
    const float* bv    = (const float*)d_in[8];
    const float* We    = (const float*)d_in[9];
    const float* Wskip = (const float*)d_in[10];
    const float* bskip = (const float*)d_in[11];
    const float* gamma = (const float*)d_in[12];
    const float* beta  = (const float*)d_in[13];
    const float* rmean = (const float*)d_in[14];
    const float* rvar  = (const float*)d_in[15];
    const float* Wc    = (const float*)d_in[16];
    const float* bc    = (const float*)d_in[17];
    float* out = (float*)d_out;

    const int N = in_sizes[0] / FIN;
    const int E = in_sizes[2] / FE;
    const int* srcp = ei;
    const int* dstp = ei + E;

    char* w = (char*)d_ws;
    size_t off = 0;
    auto alloc = [&](size_t bytes) { void* p = w + off; off += (bytes + 255) & ~255ull; return p; };
    bf16*  qb     = (bf16*)alloc((size_t)N * HC * sizeof(bf16));
    bf16*  kb     = (bf16*)alloc((size_t)N * HC * sizeof(bf16));
    bf16*  vb     = (bf16*)alloc((size_t)N * HC * sizeof(bf16));
    bf16*  qWe    = (bf16*)alloc((size_t)N * 128 * sizeof(bf16));
    bf16*  skip   = (bf16*)alloc((size_t)N * C * sizeof(bf16));
    int*   deg    = (int*)alloc((size_t)N * sizeof(int));
    int*   rowptr = (int*)alloc((size_t)(N + 1) * sizeof(int));
    int*   cnt2   = (int*)alloc((size_t)N * sizeof(int));
    int*   srcs   = (int*)alloc((size_t)E * sizeof(int));
    bf16*  ea_s   = (bf16*)alloc((size_t)E * FE * sizeof(bf16));
    float* accV   = (float*)alloc((size_t)N * C * sizeof(float));
    bf16*  aggEA  = (bf16*)alloc((size_t)N * 128 * sizeof(bf16));
    short* Wt     = (short*)alloc((size_t)WCOLS * FIN * sizeof(short));
    float* bias   = (float*)alloc((size_t)WCOLS * sizeof(float));
    short* Wet    = (short*)alloc((size_t)C * FIN * sizeof(short));
    short* Wct    = (short*)alloc((size_t)NCLS * C * sizeof(short));
    float* scalev = (float*)alloc((size_t)C * sizeof(float));
    float* shiftv = (float*)alloc((size_t)C * sizeof(float));

    hipMemsetAsync(deg,  0, (size_t)N * sizeof(int), stream);
    hipMemsetAsync(cnt2, 0, (size_t)N * sizeof(int), stream);

    pack_w_kernel<<<WCOLS + 64 + NCLS + 1, 128, 0, stream>>>(
        Wq, Wk, Wv, We, Wskip, bq, bk, bv, bskip, gamma, beta, rmean, rvar, Wc,
        Wt, bias, Wet, Wct, scalev, shiftv);
    qkv_mfma_kernel<<<(N + 31) / 32, 256, 0, stream>>>(x, Wt, bias, qb, kb, vb, qWe, skip, N);
    hist_kernel<<<(E + 255) / 256, 256, 0, stream>>>(dstp, deg, E);
    scan_kernel<<<1, 1024, 0, stream>>>(deg, rowptr, N);
    scatter_kernel<<<(E * 32 + 255) / 256, 256, 0, stream>>>(srcp, dstp, ea, rowptr, cnt2, srcs, ea_s, E);
    node_agg_kernel<<<(N + 3) / 4, 256, 0, stream>>>(srcs, rowptr, ea_s, qb, kb, vb, qWe, accV, aggEA, N);
    final_kernel<<<(N + 15) / 16, 256, 0, stream>>>(aggEA, accV, skip, Wet, Wct, scalev, shiftv, bc, out, N);
}

// Round 7
// 256.605 us; speedup vs baseline: 4.8944x; 1.3267x over previous
//
#include <hip/hip_runtime.h>
#include <hip/hip_bf16.h>

#define H 4
#define C 64
#define HC 256
#define FIN 128
#define FE 32
#define NCLS 16
#define BN_EPS 1e-5f
#define WCOLS 960   // 256 q | 256 k | 256 v | 128 qWe | 64 skip

typedef __hip_bfloat16 bf16;
typedef __attribute__((ext_vector_type(8))) short short8v;
typedef __attribute__((ext_vector_type(4))) short short4v;
typedef __attribute__((ext_vector_type(2))) short short2v;
typedef __attribute__((ext_vector_type(4))) float floatx4;

__device__ __forceinline__ float b2f(bf16 v) { return __bfloat162float(v); }
__device__ __forceinline__ float bs2f(short s) {
    unsigned u = ((unsigned)(unsigned short)s) << 16;
    return __uint_as_float(u);
}
__device__ __forceinline__ short f2bs(float f) {
    bf16 h = __float2bfloat16(f);
    return *reinterpret_cast<short*>(&h);
}

// ------- pack: Wt[960][128] bf16 + bias[960] + Wet[64][128] + Wct[16][64] + BN scale/shift -------
__global__ __launch_bounds__(128) void pack_w_kernel(
    const float* __restrict__ Wq, const float* __restrict__ Wk, const float* __restrict__ Wv,
    const float* __restrict__ We, const float* __restrict__ Wskip,
    const float* __restrict__ bq, const float* __restrict__ bk, const float* __restrict__ bv,
    const float* __restrict__ bskip,
    const float* __restrict__ gamma, const float* __restrict__ beta,
    const float* __restrict__ rmean, const float* __restrict__ rvar,
    const float* __restrict__ Wc,
    short* __restrict__ Wt, float* __restrict__ bias,
    short* __restrict__ Wet, short* __restrict__ Wct,
    float* __restrict__ scalev, float* __restrict__ shiftv)
{
    const int bid = blockIdx.x;
    const int t = threadIdx.x;       // 0..127
    if (bid < WCOLS) {
        const int col = bid;
        float val, b = 0.f;
        if (col < 256)      { val = Wq[t * HC + col]; b = bq[col]; }
        else if (col < 512) { val = Wk[t * HC + col - 256]; b = bk[col - 256]; }
        else if (col < 768) { val = Wv[t * HC + col - 512]; b = bv[col - 512]; }
        else if (col < 896) {
            int j = col - 768, h = j >> 5, f = j & 31;
            float acc = 0.f;
#pragma unroll 8
            for (int c = 0; c < C; ++c) acc += Wq[t * HC + h * C + c] * We[f * HC + h * C + c];
            val = acc;
            acc = 0.f;
            for (int c = 0; c < C; ++c) acc += bq[h * C + c] * We[f * HC + h * C + c];
            b = acc;
        }
        else { int c2 = col - 896; val = Wskip[t * C + c2]; b = bskip[c2]; }
        Wt[(size_t)col * FIN + t] = f2bs(val);
        if (t == 0) bias[col] = b;
    } else if (bid < WCOLS + 64) {
        const int c2 = bid - WCOLS;
        const int f = t & 31, h = t >> 5;
        Wet[(size_t)c2 * FIN + t] = f2bs(We[f * HC + h * C + c2]);
    } else if (bid < WCOLS + 64 + NCLS) {
        const int cls = bid - WCOLS - 64;
        if (t < C) Wct[(size_t)cls * C + t] = f2bs(Wc[t * NCLS + cls]);
    } else {
        if (t < C) {
            float inv = rsqrtf(rvar[t] + BN_EPS);
            float sc = gamma[t] * inv;
            scalev[t] = sc;
            shiftv[t] = beta[t] - rmean[t] * sc;
        }
    }
}

// ------- MFMA: [N,128] x Wt[960,128]^T -> q,k,v,qWe,skip ; 32 rows/block (B reuse x2) -------
__global__ __launch_bounds__(256) void qkv_mfma_kernel(
    const float* __restrict__ x, const short* __restrict__ Wt,
    const float* __restrict__ bias,
    bf16* __restrict__ q, bf16* __restrict__ k, bf16* __restrict__ v,
    bf16* __restrict__ qWe, bf16* __restrict__ skip, int N)
{
    const int wid = threadIdx.x >> 6;
    const int lane = threadIdx.x & 63;
    const int n0 = blockIdx.x * 32;
    const int arow = lane & 15, agrp = lane >> 4;

    short8v afrag[2][4];
#pragma unroll
    for (int rt = 0; rt < 2; ++rt) {
        int nA = n0 + rt * 16 + arow; if (nA >= N) nA = N - 1;
        const float* xrow = x + (size_t)nA * FIN + agrp * 8;
#pragma unroll
        for (int ks = 0; ks < 4; ++ks) {
            floatx4 x0 = *(const floatx4*)(xrow + ks * 32);
            floatx4 x1 = *(const floatx4*)(xrow + ks * 32 + 4);
            short8v a;
            a[0] = f2bs(x0[0]); a[1] = f2bs(x0[1]); a[2] = f2bs(x0[2]); a[3] = f2bs(x0[3]);
            a[4] = f2bs(x1[0]); a[5] = f2bs(x1[1]); a[6] = f2bs(x1[2]); a[7] = f2bs(x1[3]);
            afrag[rt][ks] = a;
        }
    }

    for (int ct = wid; ct < WCOLS / 16; ct += 4) {
        const int col0 = ct * 16;
        const int col = col0 + arow;
        const short* wp = Wt + (size_t)col * FIN + agrp * 8;
        short8v bfr[4];
#pragma unroll
        for (int ks = 0; ks < 4; ++ks) bfr[ks] = *(const short8v*)(wp + ks * 32);
        floatx4 acc0 = {0.f, 0.f, 0.f, 0.f};
        floatx4 acc1 = {0.f, 0.f, 0.f, 0.f};
#pragma unroll
        for (int ks = 0; ks < 4; ++ks) {
            acc0 = __builtin_amdgcn_mfma_f32_16x16x32_bf16(afrag[0][ks], bfr[ks], acc0, 0, 0, 0);
            acc1 = __builtin_amdgcn_mfma_f32_16x16x32_bf16(afrag[1][ks], bfr[ks], acc1, 0, 0, 0);
        }
        const float bb = bias[col];
#pragma unroll
        for (int rt = 0; rt < 2; ++rt) {
            const floatx4 acc = rt ? acc1 : acc0;
            const int rbase = n0 + rt * 16 + agrp * 4;
#pragma unroll
            for (int r = 0; r < 4; ++r) {
                const int n = rbase + r;
                if (n >= N) continue;
                const float val = acc[r] + bb;
                if (col0 < 256)      q[(size_t)n * HC + col]          = __float2bfloat16(val);
                else if (col0 < 512) k[(size_t)n * HC + col - 256]    = __float2bfloat16(val);
                else if (col0 < 768) v[(size_t)n * HC + col - 512]    = __float2bfloat16(val);
                else if (col0 < 896) qWe[(size_t)n * 128 + col - 768] = __float2bfloat16(val);
                else                 skip[(size_t)n * C + col - 896]  = __float2bfloat16(val);
            }
        }
    }
}

// ------- CSR build -------
__global__ __launch_bounds__(256) void hist_kernel(
    const int* __restrict__ dst, int* __restrict__ deg, int E)
{
    const int i = blockIdx.x * 256 + threadIdx.x;
    if (i < E) atomicAdd(&deg[dst[i]], 1);
}

// multi-block scan, phase 1: per-block (1024 elems) sums
__global__ __launch_bounds__(256) void partial_kernel(
    const int* __restrict__ deg, int* __restrict__ partials, int N)
{
    const int t = threadIdx.x;
    const int base = blockIdx.x * 1024 + t * 4;
    int s = 0;
#pragma unroll
    for (int i = 0; i < 4; ++i) {
        int idx = base + i;
        if (idx < N) s += deg[idx];
    }
#pragma unroll
    for (int off = 1; off < 64; off <<= 1) s += __shfl_xor(s, off, 64);
    __shared__ int ws[4];
    if ((t & 63) == 0) ws[t >> 6] = s;
    __syncthreads();
    if (t == 0) partials[blockIdx.x] = ws[0] + ws[1] + ws[2] + ws[3];
}

// phase 2: single small block scans the (<=256) partials -> exclusive bases, total -> rowptr[N]
__global__ __launch_bounds__(256) void scan_partials_kernel(
    int* __restrict__ partials, int* __restrict__ rowptr, int nb, int N)
{
    const int t = threadIdx.x;
    __shared__ int sm[256];
    int v = (t < nb) ? partials[t] : 0;
    sm[t] = v;
    __syncthreads();
    for (int off = 1; off < 256; off <<= 1) {
        int vv = (t >= off) ? sm[t - off] : 0;
        __syncthreads();
        sm[t] += vv;
        __syncthreads();
    }
    if (t < nb) partials[t] = sm[t] - v;   // exclusive base per block
    if (t == 255) rowptr[N] = sm[255];     // grand total
}

// phase 3: block-local scan + base -> rowptr
__global__ __launch_bounds__(256) void write_rowptr_kernel(
    const int* __restrict__ deg, const int* __restrict__ partials,
    int* __restrict__ rowptr, int N)
{
    const int t = threadIdx.x;
    const int base = blockIdx.x * 1024 + t * 4;
    int d[4];
    int s = 0;
#pragma unroll
    for (int i = 0; i < 4; ++i) {
        int idx = base + i;
        d[i] = (idx < N) ? deg[idx] : 0;
        s += d[i];
    }
    __shared__ int sm[256];
    sm[t] = s;
    __syncthreads();
    for (int off = 1; off < 256; off <<= 1) {
        int vv = (t >= off) ? sm[t - off] : 0;
        __syncthreads();
        sm[t] += vv;
        __syncthreads();
    }
    int run = partials[blockIdx.x] + sm[t] - s;
#pragma unroll
    for (int i = 0; i < 4; ++i) {
        int idx = base + i;
        if (idx < N) { rowptr[idx] = run; run += d[i]; }
    }
}

__global__ __launch_bounds__(256) void scatter_kernel(
    const int* __restrict__ src, const int* __restrict__ dst,
    const float* __restrict__ ea, const int* __restrict__ rowptr,
    int* __restrict__ cnt2, int* __restrict__ srcs, bf16* __restrict__ ea_s, int E)
{
    const int e = (blockIdx.x * 256 + threadIdx.x) >> 5;
    const int l = threadIdx.x & 31;
    if (e >= E) return;
    const int d = dst[e];
    int pos = 0;
    if (l == 0) pos = rowptr[d] + atomicAdd(&cnt2[d], 1);
    pos = __shfl(pos, 0, 32);
    if (l == 0) srcs[pos] = src[e];
    ea_s[(size_t)pos * FE + l] = __float2bfloat16(ea[(size_t)e * FE + l]);
}

// ------- fused per-node aggregation: lane = (head g, sub-lane li); 4 chan + 2 feat per lane -------
__global__ __launch_bounds__(256) void node_agg_kernel(
    const int* __restrict__ srcs, const int* __restrict__ rowptr,
    const bf16* __restrict__ ea_s,
    const bf16* __restrict__ q, const bf16* __restrict__ k, const bf16* __restrict__ v,
    const bf16* __restrict__ qWe,
    float* __restrict__ accV, bf16* __restrict__ aggEA, int N)
{
    const int w = threadIdx.x >> 6;
    const int lane = threadIdx.x & 63;
    const int d = blockIdx.x * 4 + w;
    if (d >= N) return;
    const int g = lane >> 4;     // head
    const int li = lane & 15;    // sub-lane: channels li*4..+3, features li*2..+1

    short4v qs = *(const short4v*)((const short*)q + (size_t)d * HC + g * C + li * 4);
    const float qv0 = bs2f(qs[0]), qv1 = bs2f(qs[1]), qv2 = bs2f(qs[2]), qv3 = bs2f(qs[3]);
    short2v qws = *(const short2v*)((const short*)qWe + (size_t)d * 128 + g * FE + li * 2);
    const float qw0 = bs2f(qws[0]), qw1 = bs2f(qws[1]);

    float den = 0.f;
    float a0 = 0.f, a1 = 0.f, a2 = 0.f, a3 = 0.f;
    float ag0 = 0.f, ag1 = 0.f;

    const int beg = rowptr[d], end = rowptr[d + 1];
    for (int i = beg; i < end; ++i) {
        const int s = srcs[i];
        short4v ks = *(const short4v*)((const short*)k + (size_t)s * HC + g * C + li * 4);
        short2v es = *(const short2v*)((const short*)ea_s + (size_t)i * FE + li * 2);
        const float ea0 = bs2f(es[0]), ea1 = bs2f(es[1]);
        float p = qv0 * bs2f(ks[0]) + qv1 * bs2f(ks[1])
                + qv2 * bs2f(ks[2]) + qv3 * bs2f(ks[3])
                + qw0 * ea0 + qw1 * ea1;
        p += __shfl_xor(p, 1, 64);
        p += __shfl_xor(p, 2, 64);
        p += __shfl_xor(p, 4, 64);
        p += __shfl_xor(p, 8, 64);
        const float e = exp2f(p * 0.18033688f);  // exp(p/8) = 2^(p*0.125*log2 e)
        den += e;
        short4v vs = *(const short4v*)((const short*)v + (size_t)s * HC + g * C + li * 4);
        a0 += e * bs2f(vs[0]);
        a1 += e * bs2f(vs[1]);
        a2 += e * bs2f(vs[2]);
        a3 += e * bs2f(vs[3]);
        ag0 += e * ea0; ag1 += e * ea1;
    }

    const float inv = den > 0.f ? 0.25f / den : 0.f;
    a0 *= inv; a1 *= inv; a2 *= inv; a3 *= inv;
    a0 += __shfl_xor(a0, 16, 64); a0 += __shfl_xor(a0, 32, 64);
    a1 += __shfl_xor(a1, 16, 64); a1 += __shfl_xor(a1, 32, 64);
    a2 += __shfl_xor(a2, 16, 64); a2 += __shfl_xor(a2, 32, 64);
    a3 += __shfl_xor(a3, 16, 64); a3 += __shfl_xor(a3, 32, 64);
    if (g == 0) {
        floatx4 o = {a0, a1, a2, a3};
        *(floatx4*)(accV + (size_t)d * C + li * 4) = o;
    }
    short2v so;
    so[0] = f2bs(ag0 * inv);
    so[1] = f2bs(ag1 * inv);
    *(short2v*)((short*)aggEA + (size_t)d * 128 + g * FE + li * 2) = so;
}

// ------- final: MFMA aggEA@Wet + epilogue + MFMA classifier -------
__global__ __launch_bounds__(256) void final_kernel(
    const bf16* __restrict__ aggEA, const float* __restrict__ accV,
    const bf16* __restrict__ skip,
    const short* __restrict__ Wet, const short* __restrict__ Wct,
    const float* __restrict__ scalev, const float* __restrict__ shiftv,
    const float* __restrict__ bc,
    float* __restrict__ out, int N)
{
    const int wid = threadIdx.x >> 6;
    const int lane = threadIdx.x & 63;
    const int n0 = blockIdx.x * 16;
    const int arow = lane & 15, agrp = lane >> 4;
    __shared__ short hs[16][72];   // bf16 h-tile, padded

    int nA = n0 + arow; if (nA >= N) nA = N - 1;
    const short* ap = (const short*)aggEA + (size_t)nA * 128 + agrp * 8;
    const int c0 = wid * 16;
    const int col = c0 + arow;
    const short* wp = Wet + (size_t)col * FIN + agrp * 8;
    floatx4 acc = {0.f, 0.f, 0.f, 0.f};
#pragma unroll
    for (int ks = 0; ks < 4; ++ks) {
        short8v a = *(const short8v*)(ap + ks * 32);
        short8v b = *(const short8v*)(wp + ks * 32);
        acc = __builtin_amdgcn_mfma_f32_16x16x32_bf16(a, b, acc, 0, 0, 0);
    }
    const float sc = scalev[col], sh = shiftv[col];
#pragma unroll
    for (int r = 0; r < 4; ++r) {
        const int row = agrp * 4 + r;
        int n = n0 + row; int nc = (n < N) ? n : (N - 1);
        float z = acc[r] + accV[(size_t)nc * C + col] + b2f(skip[(size_t)nc * C + col]);
        z = fmaxf(z, 0.f);
        z = z * sc + sh;
        hs[row][col] = f2bs(z);
    }
    __syncthreads();

    if (wid == 0) {
        short8v ah[2], bh[2];
#pragma unroll
        for (int ks = 0; ks < 2; ++ks) {
#pragma unroll
            for (int j = 0; j < 8; ++j) ah[ks][j] = hs[arow][ks * 32 + agrp * 8 + j];
            bh[ks] = *(const short8v*)(Wct + (size_t)arow * C + ks * 32 + agrp * 8);
        }
        floatx4 co = {0.f, 0.f, 0.f, 0.f};
        co = __builtin_amdgcn_mfma_f32_16x16x32_bf16(ah[0], bh[0], co, 0, 0, 0);
        co = __builtin_amdgcn_mfma_f32_16x16x32_bf16(ah[1], bh[1], co, 0, 0, 0);
        const float bcv = bc[arow];
#pragma unroll
        for (int r = 0; r < 4; ++r) {
            const int n = n0 + agrp * 4 + r;
            if (n < N) out[(size_t)n * NCLS + arow] = co[r] + bcv;
        }
    }
}

extern "C" void kernel_launch(void* const* d_in, const int* in_sizes, int n_in,
                              void* d_out, int out_size, void* d_ws, size_t ws_size,
                              hipStream_t stream)
{
    const float* x     = (const float*)d_in[0];
    const int*   ei    = (const int*)d_in[1];
    const float* ea    = (const float*)d_in[2];
    const float* Wq    = (const float*)d_in[3];
    const float* bq    = (const float*)d_in[4];
    const float* Wk    = (const float*)d_in[5];
    const float* bk    = (const float*)d_in[6];
    const float* Wv    = (const float*)d_in[7];
    const float* bv    = (const float*)d_in[8];
    const float* We    = (const float*)d_in[9];
    const float* Wskip = (const float*)d_in[10];
    const float* bskip = (const float*)d_in[11];
    const float* gamma = (const float*)d_in[12];
    const float* beta  = (const float*)d_in[13];
    const float* rmean = (const float*)d_in[14];
    const float* rvar  = (const float*)d_in[15];
    const float* Wc    = (const float*)d_in[16];
    const float* bc    = (const float*)d_in[17];
    float* out = (float*)d_out;

    const int N = in_sizes[0] / FIN;
    const int E = in_sizes[2] / FE;
    const int* srcp = ei;
    const int* dstp = ei + E;
    const int nb = (N + 1023) / 1024;

    char* w = (char*)d_ws;
    size_t off = 0;
    auto alloc = [&](size_t bytes) { void* p = w + off; off += (bytes + 255) & ~255ull; return p; };
    bf16*  qb     = (bf16*)alloc((size_t)N * HC * sizeof(bf16));
    bf16*  kb     = (bf16*)alloc((size_t)N * HC * sizeof(bf16));
    bf16*  vb     = (bf16*)alloc((size_t)N * HC * sizeof(bf16));
    bf16*  qWe    = (bf16*)alloc((size_t)N * 128 * sizeof(bf16));
    bf16*  skip   = (bf16*)alloc((size_t)N * C * sizeof(bf16));
    int*   deg    = (int*)alloc((size_t)N * sizeof(int));
    int*   rowptr = (int*)alloc((size_t)(N + 1) * sizeof(int));
    int*   cnt2   = (int*)alloc((size_t)N * sizeof(int));
    int*   partials = (int*)alloc(256 * sizeof(int));
    int*   srcs   = (int*)alloc((size_t)E * sizeof(int));
    bf16*  ea_s   = (bf16*)alloc((size_t)E * FE * sizeof(bf16));
    float* accV   = (float*)alloc((size_t)N * C * sizeof(float));
    bf16*  aggEA  = (bf16*)alloc((size_t)N * 128 * sizeof(bf16));
    short* Wt     = (short*)alloc((size_t)WCOLS * FIN * sizeof(short));
    float* bias   = (float*)alloc((size_t)WCOLS * sizeof(float));
    short* Wet    = (short*)alloc((size_t)C * FIN * sizeof(short));
    short* Wct    = (short*)alloc((size_t)NCLS * C * sizeof(short));
    float* scalev = (float*)alloc((size_t)C * sizeof(float));
    float* shiftv = (float*)alloc((size_t)C * sizeof(float));

    hipMemsetAsync(deg,  0, (size_t)N * sizeof(int), stream);
    hipMemsetAsync(cnt2, 0, (size_t)N * sizeof(int), stream);

    pack_w_kernel<<<WCOLS + 64 + NCLS + 1, 128, 0, stream>>>(
        Wq, Wk, Wv, We, Wskip, bq, bk, bv, bskip, gamma, beta, rmean, rvar, Wc,
        Wt, bias, Wet, Wct, scalev, shiftv);
    qkv_mfma_kernel<<<(N + 31) / 32, 256, 0, stream>>>(x, Wt, bias, qb, kb, vb, qWe, skip, N);
    hist_kernel<<<(E + 255) / 256, 256, 0, stream>>>(dstp, deg, E);
    partial_kernel<<<nb, 256, 0, stream>>>(deg, partials, N);
    scan_partials_kernel<<<1, 256, 0, stream>>>(partials, rowptr, nb, N);
    write_rowptr_kernel<<<nb, 256, 0, stream>>>(deg, partials, rowptr, N);
    scatter_kernel<<<(E * 32 + 255) / 256, 256, 0, stream>>>(srcp, dstp, ea, rowptr, cnt2, srcs, ea_s, E);
    node_agg_kernel<<<(N + 3) / 4, 256, 0, stream>>>(srcs, rowptr, ea_s, qb, kb, vb, qWe, accV, aggEA, N);
    final_kernel<<<(N + 15) / 16, 256, 0, stream>>>(aggEA, accV, skip, Wet, Wct, scalev, shiftv, bc, out, N);
}

// Round 8
// 235.559 us; speedup vs baseline: 5.3316x; 1.0893x over previous
//
#include <hip/hip_runtime.h>
#include <hip/hip_bf16.h>

#define H 4
#define C 64
#define HC 256
#define FIN 128
#define FE 32
#define NCLS 16
#define BN_EPS 1e-5f
#define WCOLS 960   // 256 q | 256 k | 256 v | 128 qWe | 64 skip

typedef __hip_bfloat16 bf16;
typedef __attribute__((ext_vector_type(8))) short short8v;
typedef __attribute__((ext_vector_type(4))) short short4v;
typedef __attribute__((ext_vector_type(2))) short short2v;
typedef __attribute__((ext_vector_type(4))) float floatx4;

__device__ __forceinline__ float b2f(bf16 v) { return __bfloat162float(v); }
__device__ __forceinline__ float bs2f(short s) {
    unsigned u = ((unsigned)(unsigned short)s) << 16;
    return __uint_as_float(u);
}
__device__ __forceinline__ short f2bs(float f) {
    bf16 h = __float2bfloat16(f);
    return *reinterpret_cast<short*>(&h);
}

// ------- pack: Wt[960][128] bf16 + bias[960] + Wet[64][128] + Wct[16][64] + BN scale/shift -------
__global__ __launch_bounds__(128) void pack_w_kernel(
    const float* __restrict__ Wq, const float* __restrict__ Wk, const float* __restrict__ Wv,
    const float* __restrict__ We, const float* __restrict__ Wskip,
    const float* __restrict__ bq, const float* __restrict__ bk, const float* __restrict__ bv,
    const float* __restrict__ bskip,
    const float* __restrict__ gamma, const float* __restrict__ beta,
    const float* __restrict__ rmean, const float* __restrict__ rvar,
    const float* __restrict__ Wc,
    short* __restrict__ Wt, float* __restrict__ bias,
    short* __restrict__ Wet, short* __restrict__ Wct,
    float* __restrict__ scalev, float* __restrict__ shiftv)
{
    const int bid = blockIdx.x;
    const int t = threadIdx.x;       // 0..127
    if (bid < WCOLS) {
        const int col = bid;
        float val, b = 0.f;
        if (col < 256)      { val = Wq[t * HC + col]; b = bq[col]; }
        else if (col < 512) { val = Wk[t * HC + col - 256]; b = bk[col - 256]; }
        else if (col < 768) { val = Wv[t * HC + col - 512]; b = bv[col - 512]; }
        else if (col < 896) {
            int j = col - 768, h = j >> 5, f = j & 31;
            float acc = 0.f;
#pragma unroll 8
            for (int c = 0; c < C; ++c) acc += Wq[t * HC + h * C + c] * We[f * HC + h * C + c];
            val = acc;
            acc = 0.f;
            for (int c = 0; c < C; ++c) acc += bq[h * C + c] * We[f * HC + h * C + c];
            b = acc;
        }
        else { int c2 = col - 896; val = Wskip[t * C + c2]; b = bskip[c2]; }
        Wt[(size_t)col * FIN + t] = f2bs(val);
        if (t == 0) bias[col] = b;
    } else if (bid < WCOLS + 64) {
        const int c2 = bid - WCOLS;
        const int f = t & 31, h = t >> 5;
        Wet[(size_t)c2 * FIN + t] = f2bs(We[f * HC + h * C + c2]);
    } else if (bid < WCOLS + 64 + NCLS) {
        const int cls = bid - WCOLS - 64;
        if (t < C) Wct[(size_t)cls * C + t] = f2bs(Wc[t * NCLS + cls]);
    } else {
        if (t < C) {
            float inv = rsqrtf(rvar[t] + BN_EPS);
            float sc = gamma[t] * inv;
            scalev[t] = sc;
            shiftv[t] = beta[t] - rmean[t] * sc;
        }
    }
}

// ------- MFMA: [N,128] x Wt[960,128]^T -> q,k,v,qWe,skip ; 32 rows/block (B reuse x2) -------
__global__ __launch_bounds__(256) void qkv_mfma_kernel(
    const float* __restrict__ x, const short* __restrict__ Wt,
    const float* __restrict__ bias,
    bf16* __restrict__ q, bf16* __restrict__ k, bf16* __restrict__ v,
    bf16* __restrict__ qWe, bf16* __restrict__ skip, int N)
{
    const int wid = threadIdx.x >> 6;
    const int lane = threadIdx.x & 63;
    const int n0 = blockIdx.x * 32;
    const int arow = lane & 15, agrp = lane >> 4;

    short8v afrag[2][4];
#pragma unroll
    for (int rt = 0; rt < 2; ++rt) {
        int nA = n0 + rt * 16 + arow; if (nA >= N) nA = N - 1;
        const float* xrow = x + (size_t)nA * FIN + agrp * 8;
#pragma unroll
        for (int ks = 0; ks < 4; ++ks) {
            floatx4 x0 = *(const floatx4*)(xrow + ks * 32);
            floatx4 x1 = *(const floatx4*)(xrow + ks * 32 + 4);
            short8v a;
            a[0] = f2bs(x0[0]); a[1] = f2bs(x0[1]); a[2] = f2bs(x0[2]); a[3] = f2bs(x0[3]);
            a[4] = f2bs(x1[0]); a[5] = f2bs(x1[1]); a[6] = f2bs(x1[2]); a[7] = f2bs(x1[3]);
            afrag[rt][ks] = a;
        }
    }

    for (int ct = wid; ct < WCOLS / 16; ct += 4) {
        const int col0 = ct * 16;
        const int col = col0 + arow;
        const short* wp = Wt + (size_t)col * FIN + agrp * 8;
        short8v bfr[4];
#pragma unroll
        for (int ks = 0; ks < 4; ++ks) bfr[ks] = *(const short8v*)(wp + ks * 32);
        floatx4 acc0 = {0.f, 0.f, 0.f, 0.f};
        floatx4 acc1 = {0.f, 0.f, 0.f, 0.f};
#pragma unroll
        for (int ks = 0; ks < 4; ++ks) {
            acc0 = __builtin_amdgcn_mfma_f32_16x16x32_bf16(afrag[0][ks], bfr[ks], acc0, 0, 0, 0);
            acc1 = __builtin_amdgcn_mfma_f32_16x16x32_bf16(afrag[1][ks], bfr[ks], acc1, 0, 0, 0);
        }
        const float bb = bias[col];
#pragma unroll
        for (int rt = 0; rt < 2; ++rt) {
            const floatx4 acc = rt ? acc1 : acc0;
            const int rbase = n0 + rt * 16 + agrp * 4;
#pragma unroll
            for (int r = 0; r < 4; ++r) {
                const int n = rbase + r;
                if (n >= N) continue;
                const float val = acc[r] + bb;
                if (col0 < 256)      q[(size_t)n * HC + col]          = __float2bfloat16(val);
                else if (col0 < 512) k[(size_t)n * HC + col - 256]    = __float2bfloat16(val);
                else if (col0 < 768) v[(size_t)n * HC + col - 512]    = __float2bfloat16(val);
                else if (col0 < 896) qWe[(size_t)n * 128 + col - 768] = __float2bfloat16(val);
                else                 skip[(size_t)n * C + col - 896]  = __float2bfloat16(val);
            }
        }
    }
}

// ------- CSR build -------
__global__ __launch_bounds__(256) void hist_kernel(
    const int* __restrict__ dst, int* __restrict__ deg, int E)
{
    const int i = blockIdx.x * 256 + threadIdx.x;
    if (i < E) atomicAdd(&deg[dst[i]], 1);
}

// multi-block scan, phase 1: per-block (1024 elems) sums
__global__ __launch_bounds__(256) void partial_kernel(
    const int* __restrict__ deg, int* __restrict__ partials, int N)
{
    const int t = threadIdx.x;
    const int base = blockIdx.x * 1024 + t * 4;
    int s = 0;
#pragma unroll
    for (int i = 0; i < 4; ++i) {
        int idx = base + i;
        if (idx < N) s += deg[idx];
    }
#pragma unroll
    for (int off = 1; off < 64; off <<= 1) s += __shfl_xor(s, off, 64);
    __shared__ int ws[4];
    if ((t & 63) == 0) ws[t >> 6] = s;
    __syncthreads();
    if (t == 0) partials[blockIdx.x] = ws[0] + ws[1] + ws[2] + ws[3];
}

// phase 2: single small block scans the (<=256) partials -> exclusive bases, total -> rowptr[N]
__global__ __launch_bounds__(256) void scan_partials_kernel(
    int* __restrict__ partials, int* __restrict__ rowptr, int nb, int N)
{
    const int t = threadIdx.x;
    __shared__ int sm[256];
    int v = (t < nb) ? partials[t] : 0;
    sm[t] = v;
    __syncthreads();
    for (int off = 1; off < 256; off <<= 1) {
        int vv = (t >= off) ? sm[t - off] : 0;
        __syncthreads();
        sm[t] += vv;
        __syncthreads();
    }
    if (t < nb) partials[t] = sm[t] - v;   // exclusive base per block
    if (t == 255) rowptr[N] = sm[255];     // grand total
}

// phase 3: block-local scan + base -> rowptr
__global__ __launch_bounds__(256) void write_rowptr_kernel(
    const int* __restrict__ deg, const int* __restrict__ partials,
    int* __restrict__ rowptr, int N)
{
    const int t = threadIdx.x;
    const int base = blockIdx.x * 1024 + t * 4;
    int d[4];
    int s = 0;
#pragma unroll
    for (int i = 0; i < 4; ++i) {
        int idx = base + i;
        d[i] = (idx < N) ? deg[idx] : 0;
        s += d[i];
    }
    __shared__ int sm[256];
    sm[t] = s;
    __syncthreads();
    for (int off = 1; off < 256; off <<= 1) {
        int vv = (t >= off) ? sm[t - off] : 0;
        __syncthreads();
        sm[t] += vv;
        __syncthreads();
    }
    int run = partials[blockIdx.x] + sm[t] - s;
#pragma unroll
    for (int i = 0; i < 4; ++i) {
        int idx = base + i;
        if (idx < N) { rowptr[idx] = run; run += d[i]; }
    }
}

// ------- scatter-lite: permute only the index, 8B per edge -------
__global__ __launch_bounds__(256) void scatter_kernel(
    const int* __restrict__ src, const int* __restrict__ dst,
    const int* __restrict__ rowptr, int* __restrict__ cnt2,
    int2* __restrict__ edg, int E)
{
    const int i = blockIdx.x * 256 + threadIdx.x;
    if (i >= E) return;
    const int d = dst[i];
    const int pos = rowptr[d] + atomicAdd(&cnt2[d], 1);
    edg[pos] = make_int2(src[i], i);
}

// ------- fused per-node aggregation: lane = (head g, sub-lane li); 4 chan + 2 feat per lane -------
__global__ __launch_bounds__(256) void node_agg_kernel(
    const int2* __restrict__ edg, const int* __restrict__ rowptr,
    const float* __restrict__ ea,
    const bf16* __restrict__ q, const bf16* __restrict__ k, const bf16* __restrict__ v,
    const bf16* __restrict__ qWe,
    float* __restrict__ accV, bf16* __restrict__ aggEA, int N)
{
    const int w = threadIdx.x >> 6;
    const int lane = threadIdx.x & 63;
    const int d = blockIdx.x * 4 + w;
    if (d >= N) return;
    const int g = lane >> 4;     // head
    const int li = lane & 15;    // sub-lane: channels li*4..+3, features li*2..+1

    short4v qs = *(const short4v*)((const short*)q + (size_t)d * HC + g * C + li * 4);
    const float qv0 = bs2f(qs[0]), qv1 = bs2f(qs[1]), qv2 = bs2f(qs[2]), qv3 = bs2f(qs[3]);
    short2v qws = *(const short2v*)((const short*)qWe + (size_t)d * 128 + g * FE + li * 2);
    const float qw0 = bs2f(qws[0]), qw1 = bs2f(qws[1]);

    float den = 0.f;
    float a0 = 0.f, a1 = 0.f, a2 = 0.f, a3 = 0.f;
    float ag0 = 0.f, ag1 = 0.f;

    const int beg = rowptr[d], end = rowptr[d + 1];
    for (int i = beg; i < end; ++i) {
        const int2 se = edg[i];
        const int s = se.x;
        const float2 eaf = *(const float2*)(ea + (size_t)se.y * FE + li * 2);
        const float ea0 = eaf.x, ea1 = eaf.y;
        short4v ks = *(const short4v*)((const short*)k + (size_t)s * HC + g * C + li * 4);
        float p = qv0 * bs2f(ks[0]) + qv1 * bs2f(ks[1])
                + qv2 * bs2f(ks[2]) + qv3 * bs2f(ks[3])
                + qw0 * ea0 + qw1 * ea1;
        p += __shfl_xor(p, 1, 64);
        p += __shfl_xor(p, 2, 64);
        p += __shfl_xor(p, 4, 64);
        p += __shfl_xor(p, 8, 64);
        const float e = exp2f(p * 0.18033688f);  // exp(p/8) = 2^(p*0.125*log2 e)
        den += e;
        short4v vs = *(const short4v*)((const short*)v + (size_t)s * HC + g * C + li * 4);
        a0 += e * bs2f(vs[0]);
        a1 += e * bs2f(vs[1]);
        a2 += e * bs2f(vs[2]);
        a3 += e * bs2f(vs[3]);
        ag0 += e * ea0; ag1 += e * ea1;
    }

    const float inv = den > 0.f ? 0.25f / den : 0.f;
    a0 *= inv; a1 *= inv; a2 *= inv; a3 *= inv;
    a0 += __shfl_xor(a0, 16, 64); a0 += __shfl_xor(a0, 32, 64);
    a1 += __shfl_xor(a1, 16, 64); a1 += __shfl_xor(a1, 32, 64);
    a2 += __shfl_xor(a2, 16, 64); a2 += __shfl_xor(a2, 32, 64);
    a3 += __shfl_xor(a3, 16, 64); a3 += __shfl_xor(a3, 32, 64);
    if (g == 0) {
        floatx4 o = {a0, a1, a2, a3};
        *(floatx4*)(accV + (size_t)d * C + li * 4) = o;
    }
    short2v so;
    so[0] = f2bs(ag0 * inv);
    so[1] = f2bs(ag1 * inv);
    *(short2v*)((short*)aggEA + (size_t)d * 128 + g * FE + li * 2) = so;
}

// ------- final: MFMA aggEA@Wet + epilogue + MFMA classifier -------
__global__ __launch_bounds__(256) void final_kernel(
    const bf16* __restrict__ aggEA, const float* __restrict__ accV,
    const bf16* __restrict__ skip,
    const short* __restrict__ Wet, const short* __restrict__ Wct,
    const float* __restrict__ scalev, const float* __restrict__ shiftv,
    const float* __restrict__ bc,
    float* __restrict__ out, int N)
{
    const int wid = threadIdx.x >> 6;
    const int lane = threadIdx.x & 63;
    const int n0 = blockIdx.x * 16;
    const int arow = lane & 15, agrp = lane >> 4;
    __shared__ short hs[16][72];   // bf16 h-tile, padded

    int nA = n0 + arow; if (nA >= N) nA = N - 1;
    const short* ap = (const short*)aggEA + (size_t)nA * 128 + agrp * 8;
    const int c0 = wid * 16;
    const int col = c0 + arow;
    const short* wp = Wet + (size_t)col * FIN + agrp * 8;
    floatx4 acc = {0.f, 0.f, 0.f, 0.f};
#pragma unroll
    for (int ks = 0; ks < 4; ++ks) {
        short8v a = *(const short8v*)(ap + ks * 32);
        short8v b = *(const short8v*)(wp + ks * 32);
        acc = __builtin_amdgcn_mfma_f32_16x16x32_bf16(a, b, acc, 0, 0, 0);
    }
    const float sc = scalev[col], sh = shiftv[col];
#pragma unroll
    for (int r = 0; r < 4; ++r) {
        const int row = agrp * 4 + r;
        int n = n0 + row; int nc = (n < N) ? n : (N - 1);
        float z = acc[r] + accV[(size_t)nc * C + col] + b2f(skip[(size_t)nc * C + col]);
        z = fmaxf(z, 0.f);
        z = z * sc + sh;
        hs[row][col] = f2bs(z);
    }
    __syncthreads();

    if (wid == 0) {
        short8v ah[2], bh[2];
#pragma unroll
        for (int ks = 0; ks < 2; ++ks) {
#pragma unroll
            for (int j = 0; j < 8; ++j) ah[ks][j] = hs[arow][ks * 32 + agrp * 8 + j];
            bh[ks] = *(const short8v*)(Wct + (size_t)arow * C + ks * 32 + agrp * 8);
        }
        floatx4 co = {0.f, 0.f, 0.f, 0.f};
        co = __builtin_amdgcn_mfma_f32_16x16x32_bf16(ah[0], bh[0], co, 0, 0, 0);
        co = __builtin_amdgcn_mfma_f32_16x16x32_bf16(ah[1], bh[1], co, 0, 0, 0);
        const float bcv = bc[arow];
#pragma unroll
        for (int r = 0; r < 4; ++r) {
            const int n = n0 + agrp * 4 + r;
            if (n < N) out[(size_t)n * NCLS + arow] = co[r] + bcv;
        }
    }
}

extern "C" void kernel_launch(void* const* d_in, const int* in_sizes, int n_in,
                              void* d_out, int out_size, void* d_ws, size_t ws_size,
                              hipStream_t stream)
{
    const float* x     = (const float*)d_in[0];
    const int*   ei    = (const int*)d_in[1];
    const float* ea    = (const float*)d_in[2];
    const float* Wq    = (const float*)d_in[3];
    const float* bq    = (const float*)d_in[4];
    const float* Wk    = (const float*)d_in[5];
    const float* bk    = (const float*)d_in[6];
    const float* Wv    = (const float*)d_in[7];
    const float* bv    = (const float*)d_in[8];
    const float* We    = (const float*)d_in[9];
    const float* Wskip = (const float*)d_in[10];
    const float* bskip = (const float*)d_in[11];
    const float* gamma = (const float*)d_in[12];
    const float* beta  = (const float*)d_in[13];
    const float* rmean = (const float*)d_in[14];
    const float* rvar  = (const float*)d_in[15];
    const float* Wc    = (const float*)d_in[16];
    const float* bc    = (const float*)d_in[17];
    float* out = (float*)d_out;

    const int N = in_sizes[0] / FIN;
    const int E = in_sizes[2] / FE;
    const int* srcp = ei;
    const int* dstp = ei + E;
    const int nb = (N + 1023) / 1024;

    char* w = (char*)d_ws;
    size_t off = 0;
    auto alloc = [&](size_t bytes) { void* p = w + off; off += (bytes + 255) & ~255ull; return p; };
    bf16*  qb     = (bf16*)alloc((size_t)N * HC * sizeof(bf16));
    bf16*  kb     = (bf16*)alloc((size_t)N * HC * sizeof(bf16));
    bf16*  vb     = (bf16*)alloc((size_t)N * HC * sizeof(bf16));
    bf16*  qWe    = (bf16*)alloc((size_t)N * 128 * sizeof(bf16));
    bf16*  skip   = (bf16*)alloc((size_t)N * C * sizeof(bf16));
    int*   deg    = (int*)alloc((size_t)N * sizeof(int));
    int*   rowptr = (int*)alloc((size_t)(N + 1) * sizeof(int));
    int*   cnt2   = (int*)alloc((size_t)N * sizeof(int));
    int*   partials = (int*)alloc(256 * sizeof(int));
    int2*  edg    = (int2*)alloc((size_t)E * sizeof(int2));
    float* accV   = (float*)alloc((size_t)N * C * sizeof(float));
    bf16*  aggEA  = (bf16*)alloc((size_t)N * 128 * sizeof(bf16));
    short* Wt     = (short*)alloc((size_t)WCOLS * FIN * sizeof(short));
    float* bias   = (float*)alloc((size_t)WCOLS * sizeof(float));
    short* Wet    = (short*)alloc((size_t)C * FIN * sizeof(short));
    short* Wct    = (short*)alloc((size_t)NCLS * C * sizeof(short));
    float* scalev = (float*)alloc((size_t)C * sizeof(float));
    float* shiftv = (float*)alloc((size_t)C * sizeof(float));

    hipMemsetAsync(deg,  0, (size_t)N * sizeof(int), stream);
    hipMemsetAsync(cnt2, 0, (size_t)N * sizeof(int), stream);

    pack_w_kernel<<<WCOLS + 64 + NCLS + 1, 128, 0, stream>>>(
        Wq, Wk, Wv, We, Wskip, bq, bk, bv, bskip, gamma, beta, rmean, rvar, Wc,
        Wt, bias, Wet, Wct, scalev, shiftv);
    qkv_mfma_kernel<<<(N + 31) / 32, 256, 0, stream>>>(x, Wt, bias, qb, kb, vb, qWe, skip, N);
    hist_kernel<<<(E + 255) / 256, 256, 0, stream>>>(dstp, deg, E);
    partial_kernel<<<nb, 256, 0, stream>>>(deg, partials, N);
    scan_partials_kernel<<<1, 256, 0, stream>>>(partials, rowptr, nb, N);
    write_rowptr_kernel<<<nb, 256, 0, stream>>>(deg, partials, rowptr, N);
    scatter_kernel<<<(E + 255) / 256, 256, 0, stream>>>(srcp, dstp, rowptr, cnt2, edg, E);
    node_agg_kernel<<<(N + 3) / 4, 256, 0, stream>>>(edg, rowptr, ea, qb, kb, vb, qWe, accV, aggEA, N);
    final_kernel<<<(N + 15) / 16, 256, 0, stream>>>(aggEA, accV, skip, Wet, Wct, scalev, shiftv, bc, out, N);
}